// Round 1
// 2843.331 us; speedup vs baseline: 2.2812x; 2.2812x over previous
//
#include <hip/hip_runtime.h>

#define H 128
#define N_NODES 100000
#define N_EDGES 400000
#define N_INC   800000
#define BN_EPS 1e-5f

__device__ __forceinline__ float4 ld4(const float* p) { return *(const float4*)p; }
__device__ __forceinline__ void st4(float* p, float4 v) { *(float4*)p = v; }
__device__ __forceinline__ float4 bnrelu4(float4 p, float4 sc, float4 sf) {
    float4 o;
    o.x = fmaxf(fmaf(p.x, sc.x, sf.x), 0.f);
    o.y = fmaxf(fmaf(p.y, sc.y, sf.y), 0.f);
    o.z = fmaxf(fmaf(p.z, sc.z, sf.z), 0.f);
    o.w = fmaxf(fmaf(p.w, sc.w, sf.w), 0.f);
    return o;
}
__device__ __forceinline__ unsigned short f2bf(float x) {   // round-to-nearest-even
    unsigned int u = __builtin_bit_cast(unsigned int, x);
    u += 0x7fffu + ((u >> 16) & 1u);
    return (unsigned short)(u >> 16);
}
__device__ __forceinline__ float bf2f(unsigned short s) {
    unsigned int u = ((unsigned int)s) << 16;
    return __builtin_bit_cast(float, u);
}

// ---- GEMM1: gathered concat [node_rep[nidx] | edge_rep[eidx]] (800000x256) @ W1 (256x128) -> bf16 msg ----
__global__ __launch_bounds__(256) void gemm1_kernel(
    const float* __restrict__ node_rep, const float* __restrict__ edge_rep,
    const int* __restrict__ node_idx, const int* __restrict__ edge_idx,
    const float* __restrict__ W1, unsigned short* __restrict__ out)
{
    __shared__ float As[64][36];   // pad 36: rows stay float4-aligned
    __shared__ float Ws[32][128];
    __shared__ int nidx[64], eidx[64];
    const int tid = threadIdx.x;
    const int rowBase = blockIdx.x * 64;
    if (tid < 64) {
        nidx[tid] = node_idx[rowBase + tid];
        eidx[tid] = edge_idx[rowBase + tid];
    }
    __syncthreads();
    const int tx = tid & 15, ty = tid >> 4;
    float acc[4][8] = {};
    for (int kt = 0; kt < 8; ++kt) {
#pragma unroll
        for (int i = 0; i < 2; ++i) {
            int li = tid + 256 * i;
            int r = li >> 3;
            int c4 = (li & 7) * 4;
            int col = kt * 32 + c4;
            const float* src = (col < 128)
                ? node_rep + (size_t)nidx[r] * H + col
                : edge_rep + (size_t)eidx[r] * H + (col - 128);
            st4(&As[r][c4], ld4(src));
        }
#pragma unroll
        for (int i = 0; i < 4; ++i) {
            int li = tid + 256 * i;
            int r = li >> 5, c4 = (li & 31) * 4;
            st4(&Ws[r][c4], ld4(&W1[(size_t)(kt * 32 + r) * H + c4]));
        }
        __syncthreads();
#pragma unroll
        for (int k = 0; k < 32; ++k) {
            float a[4];
#pragma unroll
            for (int i = 0; i < 4; ++i) a[i] = As[ty * 4 + i][k];
            float4 w0 = ld4(&Ws[k][tx * 8]);
            float4 w1 = ld4(&Ws[k][tx * 8 + 4]);
            float w[8] = {w0.x, w0.y, w0.z, w0.w, w1.x, w1.y, w1.z, w1.w};
#pragma unroll
            for (int i = 0; i < 4; ++i)
#pragma unroll
                for (int j = 0; j < 8; ++j) acc[i][j] = fmaf(a[i], w[j], acc[i][j]);
        }
        __syncthreads();
    }
#pragma unroll
    for (int i = 0; i < 4; ++i) {
        size_t r = (size_t)(rowBase + ty * 4 + i);
        int4 p;
        p.x = f2bf(acc[i][0]) | (f2bf(acc[i][1]) << 16);
        p.y = f2bf(acc[i][2]) | (f2bf(acc[i][3]) << 16);
        p.z = f2bf(acc[i][4]) | (f2bf(acc[i][5]) << 16);
        p.w = f2bf(acc[i][6]) | (f2bf(acc[i][7]) << 16);
        *(int4*)(out + r * H + tx * 8) = p;
    }
}

// ---- Generic Mx128 @ 128x128 GEMM. mode 0: A=A0 plain; mode 2: A=relu(A0*scale+shift) ----
__global__ __launch_bounds__(256) void gemm128_kernel(
    int M, int mode,
    const float* __restrict__ A0,
    const float* __restrict__ ss,
    const float* __restrict__ W, float* __restrict__ out)
{
    __shared__ float As[64][36];
    __shared__ float Ws[32][128];
    const int tid = threadIdx.x;
    const int tx = tid & 15, ty = tid >> 4;
    const int rowBase = blockIdx.x * 64;
    float acc[4][8] = {};
    for (int kt = 0; kt < 4; ++kt) {
#pragma unroll
        for (int i = 0; i < 2; ++i) {
            int li = tid + 256 * i;
            int r = li >> 3;
            int c4 = (li & 7) * 4;
            int col = kt * 32 + c4;
            int rg = rowBase + r;
            if (rg >= M) rg = M - 1;
            float4 v = ld4(&A0[(size_t)rg * H + col]);
            if (mode == 2) {
                float4 sc = ld4(&ss[col]);
                float4 sf = ld4(&ss[128 + col]);
                v = bnrelu4(v, sc, sf);
            }
            st4(&As[r][c4], v);
        }
#pragma unroll
        for (int i = 0; i < 4; ++i) {
            int li = tid + 256 * i;
            int r = li >> 5, c4 = (li & 31) * 4;
            st4(&Ws[r][c4], ld4(&W[(size_t)(kt * 32 + r) * H + c4]));
        }
        __syncthreads();
#pragma unroll
        for (int k = 0; k < 32; ++k) {
            float a[4];
#pragma unroll
            for (int i = 0; i < 4; ++i) a[i] = As[ty * 4 + i][k];
            float4 w0 = ld4(&Ws[k][tx * 8]);
            float4 w1 = ld4(&Ws[k][tx * 8 + 4]);
            float w[8] = {w0.x, w0.y, w0.z, w0.w, w1.x, w1.y, w1.z, w1.w};
#pragma unroll
            for (int i = 0; i < 4; ++i)
#pragma unroll
                for (int j = 0; j < 8; ++j) acc[i][j] = fmaf(a[i], w[j], acc[i][j]);
        }
        __syncthreads();
    }
#pragma unroll
    for (int i = 0; i < 4; ++i) {
        int rg = rowBase + ty * 4 + i;
        if (rg < M) {
            st4(&out[(size_t)rg * H + tx * 8],     make_float4(acc[i][0], acc[i][1], acc[i][2], acc[i][3]));
            st4(&out[(size_t)rg * H + tx * 8 + 4], make_float4(acc[i][4], acc[i][5], acc[i][6], acc[i][7]));
        }
    }
}

// ---- column sum / sumsq over Mx128 fp32 ----
__global__ __launch_bounds__(256) void stats_kernel(const float* __restrict__ X, int M,
                                                    float* __restrict__ sums)
{
    const int tid = threadIdx.x;
    const int c = tid & 127;
    const int half = tid >> 7;
    float s = 0.f, sq = 0.f;
    for (int r = blockIdx.x * 2 + half; r < M; r += gridDim.x * 2) {
        float v = X[(size_t)r * H + c];
        s += v;
        sq = fmaf(v, v, sq);
    }
    __shared__ float sh[256];
    sh[tid] = s;
    __syncthreads();
    float stot = (tid < 128) ? sh[tid] + sh[tid + 128] : 0.f;
    __syncthreads();
    sh[tid] = sq;
    __syncthreads();
    if (tid < 128) {
        float sqtot = sh[tid] + sh[tid + 128];
        atomicAdd(&sums[c], stot);
        atomicAdd(&sums[128 + c], sqtot);
    }
}

// ---- column sum / sumsq over Mx128 bf16 ----
__global__ __launch_bounds__(256) void stats_bf16_kernel(const unsigned short* __restrict__ X,
                                                         int M, float* __restrict__ sums)
{
    const int tid = threadIdx.x;
    const int c = tid & 127;
    const int half = tid >> 7;
    float s = 0.f, sq = 0.f;
    for (int r = blockIdx.x * 2 + half; r < M; r += gridDim.x * 2) {
        float v = bf2f(X[(size_t)r * H + c]);
        s += v;
        sq = fmaf(v, v, sq);
    }
    __shared__ float sh[256];
    sh[tid] = s;
    __syncthreads();
    float stot = (tid < 128) ? sh[tid] + sh[tid + 128] : 0.f;
    __syncthreads();
    sh[tid] = sq;
    __syncthreads();
    if (tid < 128) {
        float sqtot = sh[tid] + sh[tid + 128];
        atomicAdd(&sums[c], stot);
        atomicAdd(&sums[128 + c], sqtot);
    }
}

__global__ void finalize_kernel(const float* __restrict__ sums, float invM,
                                const float* __restrict__ g, const float* __restrict__ b,
                                float* __restrict__ ss)
{
    int c = threadIdx.x;  // 128 threads
    float mean = sums[c] * invM;
    float var = fmaf(-mean, mean, sums[128 + c] * invM);
    float scale = g[c] * rsqrtf(var + BN_EPS);
    ss[c] = scale;
    ss[128 + c] = fmaf(-mean, scale, b[c]);
}

// ======================= CSR build (no atomic scatter!) =======================
__global__ void hist_kernel(const int* __restrict__ idx, int* __restrict__ cnt, int n)
{
    int i = blockIdx.x * 256 + threadIdx.x;
    if (i < n) atomicAdd(&cnt[idx[i]], 1);
}

// in-place exclusive block scan; 2048 elems/block; block totals -> aux (if non-null)
__global__ __launch_bounds__(256) void scan_block_kernel(int* __restrict__ a, int n,
                                                         int* __restrict__ aux)
{
    __shared__ int sh[2048];
    __shared__ int ts[256];
    const int t = threadIdx.x;
    const int base = blockIdx.x * 2048;
#pragma unroll
    for (int k = 0; k < 8; ++k) {
        int i = base + t + k * 256;
        sh[t + k * 256] = (i < n) ? a[i] : 0;
    }
    __syncthreads();
    int loc[8], sum = 0;
#pragma unroll
    for (int k = 0; k < 8; ++k) { loc[k] = sh[t * 8 + k]; sum += loc[k]; }
    ts[t] = sum;
    __syncthreads();
    for (int o = 1; o < 256; o <<= 1) {
        int v = (t >= o) ? ts[t - o] : 0;
        __syncthreads();
        ts[t] += v;
        __syncthreads();
    }
    int run = ts[t] - sum;  // exclusive prefix of this thread's chunk
#pragma unroll
    for (int k = 0; k < 8; ++k) {
        int i = base + t * 8 + k;
        if (i < n) a[i] = run;
        run += loc[k];
    }
    if (aux != nullptr && t == 255) aux[blockIdx.x] = ts[255];
}

__global__ void scan_add_kernel(int* __restrict__ a, int n, const int* __restrict__ aux)
{
    int i = blockIdx.x * 256 + threadIdx.x;
    if (i < n) a[i] += aux[i >> 11];
}

// after fill: off[s] = end(s); gather uses [s==0?0:off[s-1], off[s])
__global__ void fill_kernel(const int* __restrict__ idx, int* __restrict__ off,
                            int* __restrict__ list, int n)
{
    int i = blockIdx.x * 256 + threadIdx.x;
    if (i < n) {
        int p = atomicAdd(&off[idx[i]], 1);
        list[p] = i;
    }
}

// ---- gather_edge: catm[e]=sum bnrelu(msg_i); yedge[e]=(1+eps2)*edge_rep[e]+sum node_rep[nidx_i]
__global__ __launch_bounds__(256) void gather_edge_kernel(
    const unsigned short* __restrict__ msg, const float* __restrict__ node_rep,
    const float* __restrict__ edge_rep, const int* __restrict__ node_idx,
    const int* __restrict__ eoff, const int* __restrict__ elist,
    const float* __restrict__ ss, const float* __restrict__ eps2p,
    float* __restrict__ catm, float* __restrict__ yedge)
{
    const int t = threadIdx.x;
    const int sub = t >> 5;                 // 8 edges / block
    const int lane = t & 31;
    const int e = blockIdx.x * 8 + sub;     // grid = 50000 exact
    const int c = lane * 4;
    const int s = (e == 0) ? 0 : eoff[e - 1];
    const int en = eoff[e];
    const float4 sc = ld4(&ss[c]);
    const float4 sf = ld4(&ss[128 + c]);
    float4 macc = make_float4(0.f, 0.f, 0.f, 0.f);
    float4 lacc = make_float4(0.f, 0.f, 0.f, 0.f);
    int idx = (s < en) ? elist[s] : 0;
    for (int j = s; j < en; ++j) {
        int idxn = (j + 1 < en) ? elist[j + 1] : 0;   // prefetch next incidence id
        int n = node_idx[idx];
        ushort4 mb = *(const ushort4*)(msg + (size_t)idx * H + c);
        float4 nv = ld4(&node_rep[(size_t)n * H + c]);
        float4 p = make_float4(bf2f(mb.x), bf2f(mb.y), bf2f(mb.z), bf2f(mb.w));
        float4 m = bnrelu4(p, sc, sf);
        macc.x += m.x; macc.y += m.y; macc.z += m.z; macc.w += m.w;
        lacc.x += nv.x; lacc.y += nv.y; lacc.z += nv.z; lacc.w += nv.w;
        idx = idxn;
    }
    st4(&catm[(size_t)e * H + c], macc);
    const float eps = eps2p[0];
    float4 er = ld4(&edge_rep[(size_t)e * H + c]);
    float4 y;
    y.x = fmaf(eps, er.x, er.x + lacc.x);
    y.y = fmaf(eps, er.y, er.y + lacc.y);
    y.z = fmaf(eps, er.z, er.z + lacc.z);
    y.w = fmaf(eps, er.w, er.w + lacc.w);
    st4(&yedge[(size_t)e * H + c], y);
}

// ---- gather_node: xnode[n]=(1+eps1)*node_rep[n] + sum_i (catm[eidx_i] - bnrelu(msg_i))
__global__ __launch_bounds__(256) void gather_node_kernel(
    const unsigned short* __restrict__ msg, const float* __restrict__ catm,
    const float* __restrict__ node_rep, const int* __restrict__ edge_idx,
    const int* __restrict__ noff, const int* __restrict__ nlist,
    const float* __restrict__ ss, const float* __restrict__ eps1p,
    float* __restrict__ xnode)
{
    const int t = threadIdx.x;
    const int sub = t >> 5;                 // 8 nodes / block
    const int lane = t & 31;
    const int n = blockIdx.x * 8 + sub;     // grid = 12500 exact
    const int c = lane * 4;
    const int s = (n == 0) ? 0 : noff[n - 1];
    const int en = noff[n];
    const float4 sc = ld4(&ss[c]);
    const float4 sf = ld4(&ss[128 + c]);
    float4 acc = make_float4(0.f, 0.f, 0.f, 0.f);
    int idx = (s < en) ? nlist[s] : 0;
    for (int j = s; j < en; ++j) {
        int idxn = (j + 1 < en) ? nlist[j + 1] : 0;
        int e = edge_idx[idx];
        ushort4 mb = *(const ushort4*)(msg + (size_t)idx * H + c);
        float4 cv = ld4(&catm[(size_t)e * H + c]);
        float4 p = make_float4(bf2f(mb.x), bf2f(mb.y), bf2f(mb.z), bf2f(mb.w));
        float4 m = bnrelu4(p, sc, sf);      // bit-identical to the value summed into catm
        acc.x += cv.x - m.x; acc.y += cv.y - m.y;
        acc.z += cv.z - m.z; acc.w += cv.w - m.w;
        idx = idxn;
    }
    const float eps = eps1p[0];
    float4 nr = ld4(&node_rep[(size_t)n * H + c]);
    float4 x;
    x.x = fmaf(eps, nr.x, nr.x + acc.x);
    x.y = fmaf(eps, nr.y, nr.y + acc.y);
    x.z = fmaf(eps, nr.z, nr.z + acc.z);
    x.w = fmaf(eps, nr.w, nr.w + acc.w);
    st4(&xnode[(size_t)n * H + c], x);
}

// ---- final bn_relu apply -> fp32 out ----
__global__ __launch_bounds__(256) void apply_kernel(const float* __restrict__ pre,
                                                    const float* __restrict__ ss,
                                                    float* __restrict__ out, int M)
{
    size_t gid = (size_t)blockIdx.x * 256 + threadIdx.x;
    size_t r = gid >> 5;
    int c = (int)(gid & 31) * 4;
    if (r >= (size_t)M) return;
    float4 p = ld4(&pre[r * H + c]);
    float4 sc = ld4(&ss[c]);
    float4 sf = ld4(&ss[128 + c]);
    st4(&out[r * H + c], bnrelu4(p, sc, sf));
}

extern "C" void kernel_launch(void* const* d_in, const int* in_sizes, int n_in,
                              void* d_out, int out_size, void* d_ws, size_t ws_size,
                              hipStream_t stream)
{
    const float* node_rep = (const float*)d_in[0];
    const float* edge_rep = (const float*)d_in[1];
    const int*   node_idx = (const int*)d_in[2];
    const int*   edge_idx = (const int*)d_in[3];
    const float* W1  = (const float*)d_in[4];
    const float* g1  = (const float*)d_in[5];
    const float* b1  = (const float*)d_in[6];
    const float* W2a = (const float*)d_in[7];
    const float* g2a = (const float*)d_in[8];
    const float* b2a = (const float*)d_in[9];
    const float* W2b = (const float*)d_in[10];
    const float* g2b = (const float*)d_in[11];
    const float* b2b = (const float*)d_in[12];
    const float* W3a = (const float*)d_in[13];
    const float* g3a = (const float*)d_in[14];
    const float* b3a = (const float*)d_in[15];
    const float* W3b = (const float*)d_in[16];
    const float* g3b = (const float*)d_in[17];
    const float* b3b = (const float*)d_in[18];
    const float* eps1 = (const float*)d_in[19];
    const float* eps2 = (const float*)d_in[20];

    float* ws = (float*)d_ws;
    // layout (float-slot offsets):
    unsigned short* msgb = (unsigned short*)ws;        // 800000*128 bf16 (51.2M slots)
    float* catm  = ws + (size_t) 51200000;             // 400000*128 f
    float* yedge = ws + (size_t)102400000;             // 400000*128 f
    float* xnode = ws + (size_t)153600000;             // 100000*128 f
    // edge CSR lives in the xnode region (dead before gather_node writes xnode):
    int* eoff  = (int*)(ws + (size_t)153600000);       // 400000
    int* elist = (int*)(ws + (size_t)154000000);       // 800000
    float* stat = ws + (size_t)166400000;              // 5*256 sums + 5*256 ss
    int* noff  = (int*)(ws + (size_t)166402560);       // 100000
    int* nlist = (int*)(ws + (size_t)166502560);       // 800000
    int* eaux  = (int*)(ws + (size_t)167302560);       // 256
    int* naux  = (int*)(ws + (size_t)167302816);       // 256

    // post-gather reuse:
    float* e1 = catm;           // first edge-gemm out (catm dead after gather_node)
    float* e2 = (float*)msgb;   // second edge-gemm out (msgb dead after gather_node)
    float* n1 = catm;           // first node-gemm out (e1 dead after second edge gemm)
    float* n2 = catm + (size_t)12800000;

    float* sums0 = stat +    0; float* ss0 = stat + 1280;
    float* sums1 = stat +  256; float* ss1 = stat + 1536;
    float* sums2 = stat +  512; float* ss2 = stat + 1792;
    float* sums3 = stat +  768; float* ss3 = stat + 2048;
    float* sums4 = stat + 1024; float* ss4 = stat + 2304;

    float* out_node = (float*)d_out;
    float* out_edge = out_node + (size_t)N_NODES * H;

    // tiny zero-inits only (no 460 MB accumulator memset anymore)
    hipMemsetAsync(stat, 0, 1280 * sizeof(float), stream);
    hipMemsetAsync(eoff, 0, (size_t)N_EDGES * sizeof(int), stream);
    hipMemsetAsync(noff, 0, (size_t)N_NODES * sizeof(int), stream);

    // ---- CSR build: edges (196 scan blocks) and nodes (49 scan blocks) ----
    hist_kernel<<<N_INC / 256, 256, 0, stream>>>(edge_idx, eoff, N_INC);
    scan_block_kernel<<<196, 256, 0, stream>>>(eoff, N_EDGES, eaux);
    scan_block_kernel<<<1, 256, 0, stream>>>(eaux, 196, nullptr);
    scan_add_kernel<<<(N_EDGES + 255) / 256, 256, 0, stream>>>(eoff, N_EDGES, eaux);
    fill_kernel<<<N_INC / 256, 256, 0, stream>>>(edge_idx, eoff, elist, N_INC);

    hist_kernel<<<N_INC / 256, 256, 0, stream>>>(node_idx, noff, N_INC);
    scan_block_kernel<<<49, 256, 0, stream>>>(noff, N_NODES, naux);
    scan_block_kernel<<<1, 256, 0, stream>>>(naux, 49, nullptr);
    scan_add_kernel<<<(N_NODES + 255) / 256, 256, 0, stream>>>(noff, N_NODES, naux);
    fill_kernel<<<N_INC / 256, 256, 0, stream>>>(node_idx, noff, nlist, N_INC);

    // ---- layer 1: gathered concat GEMM -> bf16 msg (pre-BN); BN1 stats ----
    gemm1_kernel<<<N_INC / 64, 256, 0, stream>>>(node_rep, edge_rep, node_idx, edge_idx, W1, msgb);
    stats_bf16_kernel<<<512, 256, 0, stream>>>(msgb, N_INC, sums0);
    finalize_kernel<<<1, 128, 0, stream>>>(sums0, 1.0f / N_INC, g1, b1, ss0);

    // ---- dense gathers (BN1 fused; y/x residual fused) ----
    gather_edge_kernel<<<N_EDGES / 8, 256, 0, stream>>>(msgb, node_rep, edge_rep, node_idx,
                                                        eoff, elist, ss0, eps2, catm, yedge);
    gather_node_kernel<<<N_NODES / 8, 256, 0, stream>>>(msgb, catm, node_rep, edge_idx,
                                                        noff, nlist, ss0, eps1, xnode);

    // ---- edge head: yedge @ W3a -> e1; bnrelu(e1) @ W3b -> e2; apply ----
    gemm128_kernel<<<N_EDGES / 64, 256, 0, stream>>>(N_EDGES, 0, yedge, nullptr, W3a, e1);
    stats_kernel<<<512, 256, 0, stream>>>(e1, N_EDGES, sums3);
    finalize_kernel<<<1, 128, 0, stream>>>(sums3, 1.0f / N_EDGES, g3a, b3a, ss3);
    gemm128_kernel<<<N_EDGES / 64, 256, 0, stream>>>(N_EDGES, 2, e1, ss3, W3b, e2);
    stats_kernel<<<512, 256, 0, stream>>>(e2, N_EDGES, sums4);
    finalize_kernel<<<1, 128, 0, stream>>>(sums4, 1.0f / N_EDGES, g3b, b3b, ss4);
    apply_kernel<<<N_EDGES / 8, 256, 0, stream>>>(e2, ss4, out_edge, N_EDGES);

    // ---- node head: xnode @ W2a -> n1; bnrelu(n1) @ W2b -> n2; apply ----
    gemm128_kernel<<<(N_NODES + 63) / 64, 256, 0, stream>>>(N_NODES, 0, xnode, nullptr, W2a, n1);
    stats_kernel<<<512, 256, 0, stream>>>(n1, N_NODES, sums1);
    finalize_kernel<<<1, 128, 0, stream>>>(sums1, 1.0f / N_NODES, g2a, b2a, ss1);
    gemm128_kernel<<<(N_NODES + 63) / 64, 256, 0, stream>>>(N_NODES, 2, n1, ss1, W2b, n2);
    stats_kernel<<<512, 256, 0, stream>>>(n2, N_NODES, sums2);
    finalize_kernel<<<1, 128, 0, stream>>>(sums2, 1.0f / N_NODES, g2b, b2b, ss2);
    apply_kernel<<<N_NODES / 8, 256, 0, stream>>>(n2, ss2, out_node, N_NODES);
}

// Round 2
// 2356.472 us; speedup vs baseline: 2.7525x; 1.2066x over previous
//
#include <hip/hip_runtime.h>

#define H 128
#define N_NODES 100000
#define N_EDGES 400000
#define N_INC   800000
#define BN_EPS 1e-5f

typedef __attribute__((ext_vector_type(8))) __bf16 bf16x8;
typedef __attribute__((ext_vector_type(4))) float f32x4;

__device__ __forceinline__ float4 ld4(const float* p) { return *(const float4*)p; }
__device__ __forceinline__ void st4(float* p, float4 v) { *(float4*)p = v; }
__device__ __forceinline__ float4 bnrelu4(float4 p, float4 sc, float4 sf) {
    float4 o;
    o.x = fmaxf(fmaf(p.x, sc.x, sf.x), 0.f);
    o.y = fmaxf(fmaf(p.y, sc.y, sf.y), 0.f);
    o.z = fmaxf(fmaf(p.z, sc.z, sf.z), 0.f);
    o.w = fmaxf(fmaf(p.w, sc.w, sf.w), 0.f);
    return o;
}
__device__ __forceinline__ unsigned short f2bf(float x) {   // round-to-nearest-even
    unsigned int u = __builtin_bit_cast(unsigned int, x);
    u += 0x7fffu + ((u >> 16) & 1u);
    return (unsigned short)(u >> 16);
}
__device__ __forceinline__ float bf2f(unsigned short s) {
    unsigned int u = ((unsigned int)s) << 16;
    return __builtin_bit_cast(float, u);
}

// ---- W transpose + bf16 convert: Wt[n*K + k] = bf16(W[k*128 + n]) ----
__global__ void wtrans_kernel(const float* __restrict__ W, unsigned short* __restrict__ Wt,
                              int kbits)
{
    int i = blockIdx.x * 256 + threadIdx.x;   // grid sized exactly to 128<<kbits
    int K = 1 << kbits;
    int n = i >> kbits;
    int k = i & (K - 1);
    Wt[i] = f2bf(W[(size_t)k * H + n]);
}

// ======================= MFMA GEMMs (split-bf16 A, bf16 W, fp32 accum) =======================
// Block tile: 128 rows x 128 cols. 4 waves; wave w owns rows [w*32, w*32+32) = 2 row-tiles x 8 col-tiles.
// LDS XOR swizzle (ushort-index granularity 8): idx = row*64 + (kcol ^ ((row&7)<<3)) -> conflict-free b128.

// ---- GEMM1: gathered concat [node_rep[nidx]|edge_rep[eidx]] (800000x256) @ W1 -> bf16 msg ----
__global__ __launch_bounds__(256) void gemm1_mfma(
    const float* __restrict__ node_rep, const float* __restrict__ edge_rep,
    const int* __restrict__ node_idx, const int* __restrict__ edge_idx,
    const unsigned short* __restrict__ Wt,   // [128 n][256 k] bf16
    unsigned short* __restrict__ out)
{
    __shared__ unsigned short Ah[128 * 64];
    __shared__ unsigned short Al[128 * 64];
    __shared__ unsigned short Ws[128 * 64];
    __shared__ int nidxs[128], eidxs[128];
    const int tid = threadIdx.x;
    const int rowBase = blockIdx.x * 128;
    if (tid < 128) {
        nidxs[tid] = node_idx[rowBase + tid];
        eidxs[tid] = edge_idx[rowBase + tid];
    }
    __syncthreads();
    const int lane = tid & 63;
    const int l15 = lane & 15;
    const int kb = lane >> 4;
    const int m0 = (tid >> 6) * 32;
    const int sr = tid >> 4;          // staging: 16 rows/pass
    const int sc = (tid & 15) * 4;    // staging: 4 k-elems/thread
    f32x4 acc[2][8];
#pragma unroll
    for (int i = 0; i < 2; ++i)
#pragma unroll
        for (int j = 0; j < 8; ++j) acc[i][j] = (f32x4){0.f, 0.f, 0.f, 0.f};

    for (int ch = 0; ch < 4; ++ch) {
        const int kc0 = ch * 64;
#pragma unroll
        for (int p = 0; p < 8; ++p) {
            int r = p * 16 + sr;
            int kg = kc0 + sc;
            const float* src = (kg < 128)
                ? node_rep + (size_t)nidxs[r] * H + kg
                : edge_rep + (size_t)eidxs[r] * H + (kg - 128);
            float4 v = ld4(src);
            unsigned short h0 = f2bf(v.x), h1 = f2bf(v.y), h2 = f2bf(v.z), h3 = f2bf(v.w);
            unsigned int hw0 = h0 | ((unsigned int)h1 << 16);
            unsigned int hw1 = h2 | ((unsigned int)h3 << 16);
            unsigned int lw0 = f2bf(v.x - bf2f(h0)) | ((unsigned int)f2bf(v.y - bf2f(h1)) << 16);
            unsigned int lw1 = f2bf(v.z - bf2f(h2)) | ((unsigned int)f2bf(v.w - bf2f(h3)) << 16);
            int si = r * 64 + (sc ^ ((r & 7) << 3));
            *(uint2*)&Ah[si] = make_uint2(hw0, hw1);
            *(uint2*)&Al[si] = make_uint2(lw0, lw1);
            uint2 wv = *(const uint2*)&Wt[(size_t)r * 256 + kc0 + sc];   // n = r here
            *(uint2*)&Ws[si] = wv;
        }
        __syncthreads();
#pragma unroll
        for (int ks = 0; ks < 2; ++ks) {
            const int ko = ks * 32 + kb * 8;
            bf16x8 bfrag[8];
#pragma unroll
            for (int ct = 0; ct < 8; ++ct) {
                int n = ct * 16 + l15;
                bfrag[ct] = *(const bf16x8*)&Ws[n * 64 + (ko ^ ((n & 7) << 3))];
            }
#pragma unroll
            for (int rt = 0; rt < 2; ++rt) {
                int r = m0 + rt * 16 + l15;
                int ai = r * 64 + (ko ^ ((r & 7) << 3));
                bf16x8 ah = *(const bf16x8*)&Ah[ai];
                bf16x8 al = *(const bf16x8*)&Al[ai];
#pragma unroll
                for (int ct = 0; ct < 8; ++ct) {
                    acc[rt][ct] = __builtin_amdgcn_mfma_f32_16x16x32_bf16(ah, bfrag[ct], acc[rt][ct], 0, 0, 0);
                    acc[rt][ct] = __builtin_amdgcn_mfma_f32_16x16x32_bf16(al, bfrag[ct], acc[rt][ct], 0, 0, 0);
                }
            }
        }
        __syncthreads();
    }
    // D: row = (lane>>4)*4 + j, col = lane&15  (per 16x16 tile)
#pragma unroll
    for (int rt = 0; rt < 2; ++rt) {
        int rg = rowBase + m0 + rt * 16 + kb * 4;
#pragma unroll
        for (int j = 0; j < 4; ++j)
#pragma unroll
            for (int ct = 0; ct < 8; ++ct)
                out[(size_t)(rg + j) * H + ct * 16 + l15] = f2bf(acc[rt][ct][j]);
    }
}

// ---- Head GEMM: Mx128 @ 128x128. mode 0: A=A0; mode 2: A=relu(A0*scale+shift) ----
__global__ __launch_bounds__(256) void gemmh_mfma(
    int M, int mode, const float* __restrict__ A0, const float* __restrict__ ss,
    const unsigned short* __restrict__ Wt,   // [128 n][128 k] bf16
    float* __restrict__ out)
{
    __shared__ unsigned short Ah[128 * 64];
    __shared__ unsigned short Al[128 * 64];
    __shared__ unsigned short Ws[128 * 64];
    const int tid = threadIdx.x;
    const int rowBase = blockIdx.x * 128;
    const int lane = tid & 63;
    const int l15 = lane & 15;
    const int kb = lane >> 4;
    const int m0 = (tid >> 6) * 32;
    const int sr = tid >> 4;
    const int sc = (tid & 15) * 4;
    f32x4 acc[2][8];
#pragma unroll
    for (int i = 0; i < 2; ++i)
#pragma unroll
        for (int j = 0; j < 8; ++j) acc[i][j] = (f32x4){0.f, 0.f, 0.f, 0.f};

    for (int ch = 0; ch < 2; ++ch) {
        const int kc0 = ch * 64;
#pragma unroll
        for (int p = 0; p < 8; ++p) {
            int r = p * 16 + sr;
            int kg = kc0 + sc;
            int rg = rowBase + r;
            if (rg >= M) rg = M - 1;
            float4 v = ld4(&A0[(size_t)rg * H + kg]);
            if (mode == 2) v = bnrelu4(v, ld4(&ss[kg]), ld4(&ss[128 + kg]));
            unsigned short h0 = f2bf(v.x), h1 = f2bf(v.y), h2 = f2bf(v.z), h3 = f2bf(v.w);
            unsigned int hw0 = h0 | ((unsigned int)h1 << 16);
            unsigned int hw1 = h2 | ((unsigned int)h3 << 16);
            unsigned int lw0 = f2bf(v.x - bf2f(h0)) | ((unsigned int)f2bf(v.y - bf2f(h1)) << 16);
            unsigned int lw1 = f2bf(v.z - bf2f(h2)) | ((unsigned int)f2bf(v.w - bf2f(h3)) << 16);
            int si = r * 64 + (sc ^ ((r & 7) << 3));
            *(uint2*)&Ah[si] = make_uint2(hw0, hw1);
            *(uint2*)&Al[si] = make_uint2(lw0, lw1);
            uint2 wv = *(const uint2*)&Wt[(size_t)r * 128 + kc0 + sc];
            *(uint2*)&Ws[si] = wv;
        }
        __syncthreads();
#pragma unroll
        for (int ks = 0; ks < 2; ++ks) {
            const int ko = ks * 32 + kb * 8;
            bf16x8 bfrag[8];
#pragma unroll
            for (int ct = 0; ct < 8; ++ct) {
                int n = ct * 16 + l15;
                bfrag[ct] = *(const bf16x8*)&Ws[n * 64 + (ko ^ ((n & 7) << 3))];
            }
#pragma unroll
            for (int rt = 0; rt < 2; ++rt) {
                int r = m0 + rt * 16 + l15;
                int ai = r * 64 + (ko ^ ((r & 7) << 3));
                bf16x8 ah = *(const bf16x8*)&Ah[ai];
                bf16x8 al = *(const bf16x8*)&Al[ai];
#pragma unroll
                for (int ct = 0; ct < 8; ++ct) {
                    acc[rt][ct] = __builtin_amdgcn_mfma_f32_16x16x32_bf16(ah, bfrag[ct], acc[rt][ct], 0, 0, 0);
                    acc[rt][ct] = __builtin_amdgcn_mfma_f32_16x16x32_bf16(al, bfrag[ct], acc[rt][ct], 0, 0, 0);
                }
            }
        }
        __syncthreads();
    }
#pragma unroll
    for (int rt = 0; rt < 2; ++rt) {
#pragma unroll
        for (int j = 0; j < 4; ++j) {
            int rg = rowBase + m0 + rt * 16 + kb * 4 + j;
            if (rg < M) {
#pragma unroll
                for (int ct = 0; ct < 8; ++ct)
                    out[(size_t)rg * H + ct * 16 + l15] = acc[rt][ct][j];
            }
        }
    }
}

// ---- column sum / sumsq over Mx128 fp32 ----
__global__ __launch_bounds__(256) void stats_kernel(const float* __restrict__ X, int M,
                                                    float* __restrict__ sums)
{
    const int tid = threadIdx.x;
    const int c = tid & 127;
    const int half = tid >> 7;
    float s = 0.f, sq = 0.f;
    for (int r = blockIdx.x * 2 + half; r < M; r += gridDim.x * 2) {
        float v = X[(size_t)r * H + c];
        s += v;
        sq = fmaf(v, v, sq);
    }
    __shared__ float sh[256];
    sh[tid] = s;
    __syncthreads();
    float stot = (tid < 128) ? sh[tid] + sh[tid + 128] : 0.f;
    __syncthreads();
    sh[tid] = sq;
    __syncthreads();
    if (tid < 128) {
        float sqtot = sh[tid] + sh[tid + 128];
        atomicAdd(&sums[c], stot);
        atomicAdd(&sums[128 + c], sqtot);
    }
}

// ---- column sum / sumsq over Mx128 bf16 ----
__global__ __launch_bounds__(256) void stats_bf16_kernel(const unsigned short* __restrict__ X,
                                                         int M, float* __restrict__ sums)
{
    const int tid = threadIdx.x;
    const int c = tid & 127;
    const int half = tid >> 7;
    float s = 0.f, sq = 0.f;
    for (int r = blockIdx.x * 2 + half; r < M; r += gridDim.x * 2) {
        float v = bf2f(X[(size_t)r * H + c]);
        s += v;
        sq = fmaf(v, v, sq);
    }
    __shared__ float sh[256];
    sh[tid] = s;
    __syncthreads();
    float stot = (tid < 128) ? sh[tid] + sh[tid + 128] : 0.f;
    __syncthreads();
    sh[tid] = sq;
    __syncthreads();
    if (tid < 128) {
        float sqtot = sh[tid] + sh[tid + 128];
        atomicAdd(&sums[c], stot);
        atomicAdd(&sums[128 + c], sqtot);
    }
}

__global__ void finalize_kernel(const float* __restrict__ sums, float invM,
                                const float* __restrict__ g, const float* __restrict__ b,
                                float* __restrict__ ss)
{
    int c = threadIdx.x;  // 128 threads
    float mean = sums[c] * invM;
    float var = fmaf(-mean, mean, sums[128 + c] * invM);
    float scale = g[c] * rsqrtf(var + BN_EPS);
    ss[c] = scale;
    ss[128 + c] = fmaf(-mean, scale, b[c]);
}

// ======================= CSR build (no atomic scatter!) =======================
__global__ void hist_kernel(const int* __restrict__ idx, int* __restrict__ cnt, int n)
{
    int i = blockIdx.x * 256 + threadIdx.x;
    if (i < n) atomicAdd(&cnt[idx[i]], 1);
}

// in-place exclusive block scan; 2048 elems/block; block totals -> aux (if non-null)
__global__ __launch_bounds__(256) void scan_block_kernel(int* __restrict__ a, int n,
                                                         int* __restrict__ aux)
{
    __shared__ int sh[2048];
    __shared__ int ts[256];
    const int t = threadIdx.x;
    const int base = blockIdx.x * 2048;
#pragma unroll
    for (int k = 0; k < 8; ++k) {
        int i = base + t + k * 256;
        sh[t + k * 256] = (i < n) ? a[i] : 0;
    }
    __syncthreads();
    int loc[8], sum = 0;
#pragma unroll
    for (int k = 0; k < 8; ++k) { loc[k] = sh[t * 8 + k]; sum += loc[k]; }
    ts[t] = sum;
    __syncthreads();
    for (int o = 1; o < 256; o <<= 1) {
        int v = (t >= o) ? ts[t - o] : 0;
        __syncthreads();
        ts[t] += v;
        __syncthreads();
    }
    int run = ts[t] - sum;  // exclusive prefix of this thread's chunk
#pragma unroll
    for (int k = 0; k < 8; ++k) {
        int i = base + t * 8 + k;
        if (i < n) a[i] = run;
        run += loc[k];
    }
    if (aux != nullptr && t == 255) aux[blockIdx.x] = ts[255];
}

__global__ void scan_add_kernel(int* __restrict__ a, int n, const int* __restrict__ aux)
{
    int i = blockIdx.x * 256 + threadIdx.x;
    if (i < n) a[i] += aux[i >> 11];
}

// after fill: off[s] = end(s); gather uses [s==0?0:off[s-1], off[s])
__global__ void fill_kernel(const int* __restrict__ idx, int* __restrict__ off,
                            int* __restrict__ list, int n)
{
    int i = blockIdx.x * 256 + threadIdx.x;
    if (i < n) {
        int p = atomicAdd(&off[idx[i]], 1);
        list[p] = i;
    }
}

// ---- gather_edge: catm[e]=sum bnrelu(msg_i); yedge[e]=(1+eps2)*edge_rep[e]+sum node_rep[nidx_i]
__global__ __launch_bounds__(256) void gather_edge_kernel(
    const unsigned short* __restrict__ msg, const float* __restrict__ node_rep,
    const float* __restrict__ edge_rep, const int* __restrict__ node_idx,
    const int* __restrict__ eoff, const int* __restrict__ elist,
    const float* __restrict__ ss, const float* __restrict__ eps2p,
    float* __restrict__ catm, float* __restrict__ yedge)
{
    const int t = threadIdx.x;
    const int sub = t >> 5;                 // 8 edges / block
    const int lane = t & 31;
    const int e = blockIdx.x * 8 + sub;     // grid = 50000 exact
    const int c = lane * 4;
    const int s = (e == 0) ? 0 : eoff[e - 1];
    const int en = eoff[e];
    const float4 sc = ld4(&ss[c]);
    const float4 sf = ld4(&ss[128 + c]);
    float4 macc = make_float4(0.f, 0.f, 0.f, 0.f);
    float4 lacc = make_float4(0.f, 0.f, 0.f, 0.f);
    int idx = (s < en) ? elist[s] : 0;
    for (int j = s; j < en; ++j) {
        int idxn = (j + 1 < en) ? elist[j + 1] : 0;   // prefetch next incidence id
        int n = node_idx[idx];
        ushort4 mb = *(const ushort4*)(msg + (size_t)idx * H + c);
        float4 nv = ld4(&node_rep[(size_t)n * H + c]);
        float4 p = make_float4(bf2f(mb.x), bf2f(mb.y), bf2f(mb.z), bf2f(mb.w));
        float4 m = bnrelu4(p, sc, sf);
        macc.x += m.x; macc.y += m.y; macc.z += m.z; macc.w += m.w;
        lacc.x += nv.x; lacc.y += nv.y; lacc.z += nv.z; lacc.w += nv.w;
        idx = idxn;
    }
    st4(&catm[(size_t)e * H + c], macc);
    const float eps = eps2p[0];
    float4 er = ld4(&edge_rep[(size_t)e * H + c]);
    float4 y;
    y.x = fmaf(eps, er.x, er.x + lacc.x);
    y.y = fmaf(eps, er.y, er.y + lacc.y);
    y.z = fmaf(eps, er.z, er.z + lacc.z);
    y.w = fmaf(eps, er.w, er.w + lacc.w);
    st4(&yedge[(size_t)e * H + c], y);
}

// ---- gather_node: xnode[n]=(1+eps1)*node_rep[n] + sum_i (catm[eidx_i] - bnrelu(msg_i))
__global__ __launch_bounds__(256) void gather_node_kernel(
    const unsigned short* __restrict__ msg, const float* __restrict__ catm,
    const float* __restrict__ node_rep, const int* __restrict__ edge_idx,
    const int* __restrict__ noff, const int* __restrict__ nlist,
    const float* __restrict__ ss, const float* __restrict__ eps1p,
    float* __restrict__ xnode)
{
    const int t = threadIdx.x;
    const int sub = t >> 5;                 // 8 nodes / block
    const int lane = t & 31;
    const int n = blockIdx.x * 8 + sub;     // grid = 12500 exact
    const int c = lane * 4;
    const int s = (n == 0) ? 0 : noff[n - 1];
    const int en = noff[n];
    const float4 sc = ld4(&ss[c]);
    const float4 sf = ld4(&ss[128 + c]);
    float4 acc = make_float4(0.f, 0.f, 0.f, 0.f);
    int idx = (s < en) ? nlist[s] : 0;
    for (int j = s; j < en; ++j) {
        int idxn = (j + 1 < en) ? nlist[j + 1] : 0;
        int e = edge_idx[idx];
        ushort4 mb = *(const ushort4*)(msg + (size_t)idx * H + c);
        float4 cv = ld4(&catm[(size_t)e * H + c]);
        float4 p = make_float4(bf2f(mb.x), bf2f(mb.y), bf2f(mb.z), bf2f(mb.w));
        float4 m = bnrelu4(p, sc, sf);      // bit-identical to the value summed into catm
        acc.x += cv.x - m.x; acc.y += cv.y - m.y;
        acc.z += cv.z - m.z; acc.w += cv.w - m.w;
        idx = idxn;
    }
    const float eps = eps1p[0];
    float4 nr = ld4(&node_rep[(size_t)n * H + c]);
    float4 x;
    x.x = fmaf(eps, nr.x, nr.x + acc.x);
    x.y = fmaf(eps, nr.y, nr.y + acc.y);
    x.z = fmaf(eps, nr.z, nr.z + acc.z);
    x.w = fmaf(eps, nr.w, nr.w + acc.w);
    st4(&xnode[(size_t)n * H + c], x);
}

// ---- final bn_relu apply -> fp32 out ----
__global__ __launch_bounds__(256) void apply_kernel(const float* __restrict__ pre,
                                                    const float* __restrict__ ss,
                                                    float* __restrict__ out, int M)
{
    size_t gid = (size_t)blockIdx.x * 256 + threadIdx.x;
    size_t r = gid >> 5;
    int c = (int)(gid & 31) * 4;
    if (r >= (size_t)M) return;
    float4 p = ld4(&pre[r * H + c]);
    float4 sc = ld4(&ss[c]);
    float4 sf = ld4(&ss[128 + c]);
    st4(&out[r * H + c], bnrelu4(p, sc, sf));
}

extern "C" void kernel_launch(void* const* d_in, const int* in_sizes, int n_in,
                              void* d_out, int out_size, void* d_ws, size_t ws_size,
                              hipStream_t stream)
{
    const float* node_rep = (const float*)d_in[0];
    const float* edge_rep = (const float*)d_in[1];
    const int*   node_idx = (const int*)d_in[2];
    const int*   edge_idx = (const int*)d_in[3];
    const float* W1  = (const float*)d_in[4];
    const float* g1  = (const float*)d_in[5];
    const float* b1  = (const float*)d_in[6];
    const float* W2a = (const float*)d_in[7];
    const float* g2a = (const float*)d_in[8];
    const float* b2a = (const float*)d_in[9];
    const float* W2b = (const float*)d_in[10];
    const float* g2b = (const float*)d_in[11];
    const float* b2b = (const float*)d_in[12];
    const float* W3a = (const float*)d_in[13];
    const float* g3a = (const float*)d_in[14];
    const float* b3a = (const float*)d_in[15];
    const float* W3b = (const float*)d_in[16];
    const float* g3b = (const float*)d_in[17];
    const float* b3b = (const float*)d_in[18];
    const float* eps1 = (const float*)d_in[19];
    const float* eps2 = (const float*)d_in[20];

    float* ws = (float*)d_ws;
    // layout (float-slot offsets):
    unsigned short* msgb = (unsigned short*)ws;        // 800000*128 bf16 (51.2M slots)
    float* catm  = ws + (size_t) 51200000;             // 400000*128 f
    float* yedge = ws + (size_t)102400000;             // 400000*128 f
    float* xnode = ws + (size_t)153600000;             // 100000*128 f
    // edge CSR lives in the xnode region (dead before gather_node writes xnode):
    int* eoff  = (int*)(ws + (size_t)153600000);       // 400000
    int* elist = (int*)(ws + (size_t)154000000);       // 800000
    float* stat = ws + (size_t)166400000;              // 5*256 sums + 5*256 ss
    int* noff  = (int*)(ws + (size_t)166402560);       // 100000
    int* nlist = (int*)(ws + (size_t)166502560);       // 800000
    int* eaux  = (int*)(ws + (size_t)167302560);       // 256
    int* naux  = (int*)(ws + (size_t)167302816);       // 256
    // transposed bf16 weights:
    unsigned short* wt1  = (unsigned short*)(ws + (size_t)167304000);  // 128*256 bf16
    unsigned short* wt2a = (unsigned short*)(ws + (size_t)167320384);  // 128*128 bf16
    unsigned short* wt2b = (unsigned short*)(ws + (size_t)167328576);
    unsigned short* wt3a = (unsigned short*)(ws + (size_t)167336768);
    unsigned short* wt3b = (unsigned short*)(ws + (size_t)167344960);

    // post-gather reuse:
    float* e1 = catm;           // first edge-gemm out (catm dead after gather_node)
    float* e2 = (float*)msgb;   // second edge-gemm out (msgb dead after gather_node)
    float* n1 = catm;           // first node-gemm out (e1 dead after second edge gemm)
    float* n2 = catm + (size_t)12800000;

    float* sums0 = stat +    0; float* ss0 = stat + 1280;
    float* sums1 = stat +  256; float* ss1 = stat + 1536;
    float* sums2 = stat +  512; float* ss2 = stat + 1792;
    float* sums3 = stat +  768; float* ss3 = stat + 2048;
    float* sums4 = stat + 1024; float* ss4 = stat + 2304;

    float* out_node = (float*)d_out;
    float* out_edge = out_node + (size_t)N_NODES * H;

    // tiny zero-inits only
    hipMemsetAsync(stat, 0, 1280 * sizeof(float), stream);
    hipMemsetAsync(eoff, 0, (size_t)N_EDGES * sizeof(int), stream);
    hipMemsetAsync(noff, 0, (size_t)N_NODES * sizeof(int), stream);

    // ---- weight transpose + bf16 (tiny) ----
    wtrans_kernel<<<128, 256, 0, stream>>>(W1,  wt1,  8);
    wtrans_kernel<<< 64, 256, 0, stream>>>(W2a, wt2a, 7);
    wtrans_kernel<<< 64, 256, 0, stream>>>(W2b, wt2b, 7);
    wtrans_kernel<<< 64, 256, 0, stream>>>(W3a, wt3a, 7);
    wtrans_kernel<<< 64, 256, 0, stream>>>(W3b, wt3b, 7);

    // ---- CSR build: edges (196 scan blocks) and nodes (49 scan blocks) ----
    hist_kernel<<<N_INC / 256, 256, 0, stream>>>(edge_idx, eoff, N_INC);
    scan_block_kernel<<<196, 256, 0, stream>>>(eoff, N_EDGES, eaux);
    scan_block_kernel<<<1, 256, 0, stream>>>(eaux, 196, nullptr);
    scan_add_kernel<<<(N_EDGES + 255) / 256, 256, 0, stream>>>(eoff, N_EDGES, eaux);
    fill_kernel<<<N_INC / 256, 256, 0, stream>>>(edge_idx, eoff, elist, N_INC);

    hist_kernel<<<N_INC / 256, 256, 0, stream>>>(node_idx, noff, N_INC);
    scan_block_kernel<<<49, 256, 0, stream>>>(noff, N_NODES, naux);
    scan_block_kernel<<<1, 256, 0, stream>>>(naux, 49, nullptr);
    scan_add_kernel<<<(N_NODES + 255) / 256, 256, 0, stream>>>(noff, N_NODES, naux);
    fill_kernel<<<N_INC / 256, 256, 0, stream>>>(node_idx, noff, nlist, N_INC);

    // ---- layer 1: gathered concat GEMM (MFMA) -> bf16 msg (pre-BN); BN1 stats ----
    gemm1_mfma<<<N_INC / 128, 256, 0, stream>>>(node_rep, edge_rep, node_idx, edge_idx, wt1, msgb);
    stats_bf16_kernel<<<512, 256, 0, stream>>>(msgb, N_INC, sums0);
    finalize_kernel<<<1, 128, 0, stream>>>(sums0, 1.0f / N_INC, g1, b1, ss0);

    // ---- dense gathers (BN1 fused; y/x residual fused) ----
    gather_edge_kernel<<<N_EDGES / 8, 256, 0, stream>>>(msgb, node_rep, edge_rep, node_idx,
                                                        eoff, elist, ss0, eps2, catm, yedge);
    gather_node_kernel<<<N_NODES / 8, 256, 0, stream>>>(msgb, catm, node_rep, edge_idx,
                                                        noff, nlist, ss0, eps1, xnode);

    // ---- edge head: yedge @ W3a -> e1; bnrelu(e1) @ W3b -> e2; apply ----
    gemmh_mfma<<<N_EDGES / 128, 256, 0, stream>>>(N_EDGES, 0, yedge, nullptr, wt3a, e1);
    stats_kernel<<<512, 256, 0, stream>>>(e1, N_EDGES, sums3);
    finalize_kernel<<<1, 128, 0, stream>>>(sums3, 1.0f / N_EDGES, g3a, b3a, ss3);
    gemmh_mfma<<<N_EDGES / 128, 256, 0, stream>>>(N_EDGES, 2, e1, ss3, wt3b, e2);
    stats_kernel<<<512, 256, 0, stream>>>(e2, N_EDGES, sums4);
    finalize_kernel<<<1, 128, 0, stream>>>(sums4, 1.0f / N_EDGES, g3b, b3b, ss4);
    apply_kernel<<<N_EDGES / 8, 256, 0, stream>>>(e2, ss4, out_edge, N_EDGES);

    // ---- node head: xnode @ W2a -> n1; bnrelu(n1) @ W2b -> n2; apply ----
    gemmh_mfma<<<(N_NODES + 127) / 128, 256, 0, stream>>>(N_NODES, 0, xnode, nullptr, wt2a, n1);
    stats_kernel<<<512, 256, 0, stream>>>(n1, N_NODES, sums1);
    finalize_kernel<<<1, 128, 0, stream>>>(sums1, 1.0f / N_NODES, g2a, b2a, ss1);
    gemmh_mfma<<<(N_NODES + 127) / 128, 256, 0, stream>>>(N_NODES, 2, n1, ss1, wt2b, n2);
    stats_kernel<<<512, 256, 0, stream>>>(n2, N_NODES, sums2);
    finalize_kernel<<<1, 128, 0, stream>>>(sums2, 1.0f / N_NODES, g2b, b2b, ss2);
    apply_kernel<<<N_NODES / 8, 256, 0, stream>>>(n2, ss2, out_node, N_NODES);
}

// Round 3
// 1822.023 us; speedup vs baseline: 3.5599x; 1.2933x over previous
//
#include <hip/hip_runtime.h>

#define H 128
#define N_NODES 100000
#define N_EDGES 400000
#define N_INC   800000
#define BN_EPS 1e-5f

typedef __attribute__((ext_vector_type(8))) __bf16 bf16x8;
typedef __attribute__((ext_vector_type(4))) float f32x4;

__device__ __forceinline__ float4 ld4(const float* p) { return *(const float4*)p; }
__device__ __forceinline__ void st4(float* p, float4 v) { *(float4*)p = v; }
__device__ __forceinline__ float4 bnrelu4(float4 p, float4 sc, float4 sf) {
    float4 o;
    o.x = fmaxf(fmaf(p.x, sc.x, sf.x), 0.f);
    o.y = fmaxf(fmaf(p.y, sc.y, sf.y), 0.f);
    o.z = fmaxf(fmaf(p.z, sc.z, sf.z), 0.f);
    o.w = fmaxf(fmaf(p.w, sc.w, sf.w), 0.f);
    return o;
}
__device__ __forceinline__ unsigned short f2bf(float x) {   // round-to-nearest-even
    unsigned int u = __builtin_bit_cast(unsigned int, x);
    u += 0x7fffu + ((u >> 16) & 1u);
    return (unsigned short)(u >> 16);
}
__device__ __forceinline__ float bf2f(unsigned short s) {
    unsigned int u = ((unsigned int)s) << 16;
    return __builtin_bit_cast(float, u);
}

// split 8 fp32 into hi/lo bf16x8 (compiler emits v_cvt_pk_bf16_f32 for the casts)
__device__ __forceinline__ void split8(const float* a, bf16x8& h, bf16x8& l) {
#pragma unroll
    for (int j = 0; j < 8; ++j) h[j] = (__bf16)a[j];
#pragma unroll
    for (int j = 0; j < 8; ++j) l[j] = (__bf16)(a[j] - (float)h[j]);
}

// ---- W transpose + bf16 convert: Wt[n*K + k] = bf16(W[k*128 + n]) ----
__global__ void wtrans_kernel(const float* __restrict__ W, unsigned short* __restrict__ Wt,
                              int kbits)
{
    int i = blockIdx.x * 256 + threadIdx.x;   // grid sized exactly to 128<<kbits
    int K = 1 << kbits;
    int n = i >> kbits;
    int k = i & (K - 1);
    Wt[i] = f2bf(W[(size_t)k * H + n]);
}

// ======================= LDS-free direct MFMA GEMMs =======================
// 256 threads = 4 waves; wave w owns rows [blk*128 + w*32, +32): 2 row-tiles x 8 col-tiles.
// A fragments loaded straight from global (8 contiguous fp32/lane), split hi/lo bf16 in-reg.
// W fragments (bf16, pre-transposed) loaded straight from global (L1/L2-hot).
// No main-loop barriers. BN column stats fused into the epilogue.

// ---- GEMM1: gathered concat [node_rep[nidx]|edge_rep[eidx]] (800000x256) @ W1 -> bf16 msg ----
__global__ __launch_bounds__(256) void gemm1_mfma(
    const float* __restrict__ node_rep, const float* __restrict__ edge_rep,
    const int* __restrict__ node_idx, const int* __restrict__ edge_idx,
    const unsigned short* __restrict__ Wt,   // [128 n][256 k] bf16
    unsigned short* __restrict__ out, float* __restrict__ sums)
{
    const int tid = threadIdx.x;
    const int lane = tid & 63;
    const int wv = tid >> 6;
    const int l15 = lane & 15;
    const int kb = lane >> 4;
    const int ko = kb * 8;
    const int rowBase = blockIdx.x * 128 + wv * 32;
    const int r0 = rowBase + l15;
    const int r1 = rowBase + 16 + l15;
    const float* an0 = node_rep + (size_t)node_idx[r0] * H;
    const float* ae0 = edge_rep + (size_t)edge_idx[r0] * H;
    const float* an1 = node_rep + (size_t)node_idx[r1] * H;
    const float* ae1 = edge_rep + (size_t)edge_idx[r1] * H;

    f32x4 acc[2][8];
#pragma unroll
    for (int i = 0; i < 2; ++i)
#pragma unroll
        for (int j = 0; j < 8; ++j) acc[i][j] = (f32x4){0.f, 0.f, 0.f, 0.f};

#pragma unroll
    for (int ks = 0; ks < 8; ++ks) {
        const int k0 = ks * 32 + ko;
        const float* p0 = (ks < 4) ? (an0 + k0) : (ae0 + (k0 - 128));
        const float* p1 = (ks < 4) ? (an1 + k0) : (ae1 + (k0 - 128));
        float a0[8], a1[8];
        { float4 x = ld4(p0), y = ld4(p0 + 4);
          a0[0]=x.x; a0[1]=x.y; a0[2]=x.z; a0[3]=x.w; a0[4]=y.x; a0[5]=y.y; a0[6]=y.z; a0[7]=y.w; }
        { float4 x = ld4(p1), y = ld4(p1 + 4);
          a1[0]=x.x; a1[1]=x.y; a1[2]=x.z; a1[3]=x.w; a1[4]=y.x; a1[5]=y.y; a1[6]=y.z; a1[7]=y.w; }
        bf16x8 h0, l0, h1, l1;
        split8(a0, h0, l0);
        split8(a1, h1, l1);
        const unsigned short* wp = Wt + (size_t)l15 * 256 + ks * 32 + ko;
#pragma unroll
        for (int ct = 0; ct < 8; ++ct) {
            bf16x8 bw = *(const bf16x8*)(wp + ct * 16 * 256);
            acc[0][ct] = __builtin_amdgcn_mfma_f32_16x16x32_bf16(h0, bw, acc[0][ct], 0, 0, 0);
            acc[0][ct] = __builtin_amdgcn_mfma_f32_16x16x32_bf16(l0, bw, acc[0][ct], 0, 0, 0);
            acc[1][ct] = __builtin_amdgcn_mfma_f32_16x16x32_bf16(h1, bw, acc[1][ct], 0, 0, 0);
            acc[1][ct] = __builtin_amdgcn_mfma_f32_16x16x32_bf16(l1, bw, acc[1][ct], 0, 0, 0);
        }
    }

    // ---- epilogue: bf16 store + fused column stats (on the rounded values) ----
    __shared__ float sred[4][256];
    float scol[8], qcol[8];
#pragma unroll
    for (int ct = 0; ct < 8; ++ct) { scol[ct] = 0.f; qcol[ct] = 0.f; }
#pragma unroll
    for (int rt = 0; rt < 2; ++rt) {
        const int rg = rowBase + rt * 16 + kb * 4;
#pragma unroll
        for (int j = 0; j < 4; ++j) {
#pragma unroll
            for (int ct = 0; ct < 8; ++ct) {
                unsigned short us = f2bf(acc[rt][ct][j]);
                out[(size_t)(rg + j) * H + ct * 16 + l15] = us;
                float v = bf2f(us);
                scol[ct] += v;
                qcol[ct] = fmaf(v, v, qcol[ct]);
            }
        }
    }
#pragma unroll
    for (int ct = 0; ct < 8; ++ct) {
        scol[ct] += __shfl_xor(scol[ct], 16);
        scol[ct] += __shfl_xor(scol[ct], 32);
        qcol[ct] += __shfl_xor(qcol[ct], 16);
        qcol[ct] += __shfl_xor(qcol[ct], 32);
    }
    if (kb == 0) {
#pragma unroll
        for (int ct = 0; ct < 8; ++ct) {
            sred[wv][ct * 16 + l15] = scol[ct];
            sred[wv][128 + ct * 16 + l15] = qcol[ct];
        }
    }
    __syncthreads();
    float tot = sred[0][tid & 255] + sred[1][tid & 255] + sred[2][tid & 255] + sred[3][tid & 255];
    atomicAdd(&sums[tid & 255], tot);
}

// ---- Head GEMM: Mx128 @ 128x128. mode 0: A=A0; mode 2: A=relu(A0*scale+shift). fp32 out + stats ----
__global__ __launch_bounds__(256) void gemmh_mfma(
    int M, int mode, const float* __restrict__ A0, const float* __restrict__ ss,
    const unsigned short* __restrict__ Wt,   // [128 n][128 k] bf16
    float* __restrict__ out, float* __restrict__ sums)
{
    const int tid = threadIdx.x;
    const int lane = tid & 63;
    const int wv = tid >> 6;
    const int l15 = lane & 15;
    const int kb = lane >> 4;
    const int ko = kb * 8;
    const int rowBase = blockIdx.x * 128 + wv * 32;
    int r0 = rowBase + l15;       if (r0 >= M) r0 = M - 1;
    int r1 = rowBase + 16 + l15;  if (r1 >= M) r1 = M - 1;
    const float* a0p = A0 + (size_t)r0 * H;
    const float* a1p = A0 + (size_t)r1 * H;

    f32x4 acc[2][8];
#pragma unroll
    for (int i = 0; i < 2; ++i)
#pragma unroll
        for (int j = 0; j < 8; ++j) acc[i][j] = (f32x4){0.f, 0.f, 0.f, 0.f};

#pragma unroll
    for (int ks = 0; ks < 4; ++ks) {
        const int k0 = ks * 32 + ko;
        float a0[8], a1[8];
        { float4 x = ld4(a0p + k0), y = ld4(a0p + k0 + 4);
          a0[0]=x.x; a0[1]=x.y; a0[2]=x.z; a0[3]=x.w; a0[4]=y.x; a0[5]=y.y; a0[6]=y.z; a0[7]=y.w; }
        { float4 x = ld4(a1p + k0), y = ld4(a1p + k0 + 4);
          a1[0]=x.x; a1[1]=x.y; a1[2]=x.z; a1[3]=x.w; a1[4]=y.x; a1[5]=y.y; a1[6]=y.z; a1[7]=y.w; }
        if (mode == 2) {
            float4 sca = ld4(&ss[k0]), scb = ld4(&ss[k0 + 4]);
            float4 sfa = ld4(&ss[128 + k0]), sfb = ld4(&ss[128 + k0 + 4]);
            float sc[8] = {sca.x, sca.y, sca.z, sca.w, scb.x, scb.y, scb.z, scb.w};
            float sf[8] = {sfa.x, sfa.y, sfa.z, sfa.w, sfb.x, sfb.y, sfb.z, sfb.w};
#pragma unroll
            for (int j = 0; j < 8; ++j) {
                a0[j] = fmaxf(fmaf(a0[j], sc[j], sf[j]), 0.f);
                a1[j] = fmaxf(fmaf(a1[j], sc[j], sf[j]), 0.f);
            }
        }
        bf16x8 h0, l0, h1, l1;
        split8(a0, h0, l0);
        split8(a1, h1, l1);
        const unsigned short* wp = Wt + (size_t)l15 * 128 + ks * 32 + ko;
#pragma unroll
        for (int ct = 0; ct < 8; ++ct) {
            bf16x8 bw = *(const bf16x8*)(wp + ct * 16 * 128);
            acc[0][ct] = __builtin_amdgcn_mfma_f32_16x16x32_bf16(h0, bw, acc[0][ct], 0, 0, 0);
            acc[0][ct] = __builtin_amdgcn_mfma_f32_16x16x32_bf16(l0, bw, acc[0][ct], 0, 0, 0);
            acc[1][ct] = __builtin_amdgcn_mfma_f32_16x16x32_bf16(h1, bw, acc[1][ct], 0, 0, 0);
            acc[1][ct] = __builtin_amdgcn_mfma_f32_16x16x32_bf16(l1, bw, acc[1][ct], 0, 0, 0);
        }
    }

    // ---- epilogue: fp32 store (masked) + fused column stats ----
    __shared__ float sred[4][256];
    float scol[8], qcol[8];
#pragma unroll
    for (int ct = 0; ct < 8; ++ct) { scol[ct] = 0.f; qcol[ct] = 0.f; }
#pragma unroll
    for (int rt = 0; rt < 2; ++rt) {
#pragma unroll
        for (int j = 0; j < 4; ++j) {
            const int rg = rowBase + rt * 16 + kb * 4 + j;
            if (rg < M) {
#pragma unroll
                for (int ct = 0; ct < 8; ++ct) {
                    float v = acc[rt][ct][j];
                    out[(size_t)rg * H + ct * 16 + l15] = v;
                    scol[ct] += v;
                    qcol[ct] = fmaf(v, v, qcol[ct]);
                }
            }
        }
    }
#pragma unroll
    for (int ct = 0; ct < 8; ++ct) {
        scol[ct] += __shfl_xor(scol[ct], 16);
        scol[ct] += __shfl_xor(scol[ct], 32);
        qcol[ct] += __shfl_xor(qcol[ct], 16);
        qcol[ct] += __shfl_xor(qcol[ct], 32);
    }
    if (kb == 0) {
#pragma unroll
        for (int ct = 0; ct < 8; ++ct) {
            sred[wv][ct * 16 + l15] = scol[ct];
            sred[wv][128 + ct * 16 + l15] = qcol[ct];
        }
    }
    __syncthreads();
    float tot = sred[0][tid & 255] + sred[1][tid & 255] + sred[2][tid & 255] + sred[3][tid & 255];
    atomicAdd(&sums[tid & 255], tot);
}

__global__ void finalize_kernel(const float* __restrict__ sums, float invM,
                                const float* __restrict__ g, const float* __restrict__ b,
                                float* __restrict__ ss)
{
    int c = threadIdx.x;  // 128 threads
    float mean = sums[c] * invM;
    float var = fmaf(-mean, mean, sums[128 + c] * invM);
    float scale = g[c] * rsqrtf(var + BN_EPS);
    ss[c] = scale;
    ss[128 + c] = fmaf(-mean, scale, b[c]);
}

// ======================= CSR build (no atomic scatter!) =======================
__global__ void hist_kernel(const int* __restrict__ idx, int* __restrict__ cnt, int n)
{
    int i = blockIdx.x * 256 + threadIdx.x;
    if (i < n) atomicAdd(&cnt[idx[i]], 1);
}

// in-place exclusive block scan; 2048 elems/block; block totals -> aux (if non-null)
__global__ __launch_bounds__(256) void scan_block_kernel(int* __restrict__ a, int n,
                                                         int* __restrict__ aux)
{
    __shared__ int sh[2048];
    __shared__ int ts[256];
    const int t = threadIdx.x;
    const int base = blockIdx.x * 2048;
#pragma unroll
    for (int k = 0; k < 8; ++k) {
        int i = base + t + k * 256;
        sh[t + k * 256] = (i < n) ? a[i] : 0;
    }
    __syncthreads();
    int loc[8], sum = 0;
#pragma unroll
    for (int k = 0; k < 8; ++k) { loc[k] = sh[t * 8 + k]; sum += loc[k]; }
    ts[t] = sum;
    __syncthreads();
    for (int o = 1; o < 256; o <<= 1) {
        int v = (t >= o) ? ts[t - o] : 0;
        __syncthreads();
        ts[t] += v;
        __syncthreads();
    }
    int run = ts[t] - sum;  // exclusive prefix of this thread's chunk
#pragma unroll
    for (int k = 0; k < 8; ++k) {
        int i = base + t * 8 + k;
        if (i < n) a[i] = run;
        run += loc[k];
    }
    if (aux != nullptr && t == 255) aux[blockIdx.x] = ts[255];
}

__global__ void scan_add_kernel(int* __restrict__ a, int n, const int* __restrict__ aux)
{
    int i = blockIdx.x * 256 + threadIdx.x;
    if (i < n) a[i] += aux[i >> 11];
}

// after fill: off[s] = end(s); gather uses [s==0?0:off[s-1], off[s])
__global__ void fill_kernel(const int* __restrict__ idx, int* __restrict__ off,
                            int* __restrict__ list, int n)
{
    int i = blockIdx.x * 256 + threadIdx.x;
    if (i < n) {
        int p = atomicAdd(&off[idx[i]], 1);
        list[p] = i;
    }
}

// ---- gather_edge: catm[e]=sum bnrelu(msg_i); yedge[e]=(1+eps2)*edge_rep[e]+sum node_rep[nidx_i]
__global__ __launch_bounds__(256) void gather_edge_kernel(
    const unsigned short* __restrict__ msg, const float* __restrict__ node_rep,
    const float* __restrict__ edge_rep, const int* __restrict__ node_idx,
    const int* __restrict__ eoff, const int* __restrict__ elist,
    const float* __restrict__ ss, const float* __restrict__ eps2p,
    float* __restrict__ catm, float* __restrict__ yedge)
{
    const int t = threadIdx.x;
    const int sub = t >> 5;                 // 8 edges / block
    const int lane = t & 31;
    const int e = blockIdx.x * 8 + sub;     // grid = 50000 exact
    const int c = lane * 4;
    const int s = (e == 0) ? 0 : eoff[e - 1];
    const int en = eoff[e];
    const float4 sc = ld4(&ss[c]);
    const float4 sf = ld4(&ss[128 + c]);
    float4 macc = make_float4(0.f, 0.f, 0.f, 0.f);
    float4 lacc = make_float4(0.f, 0.f, 0.f, 0.f);
    int idx = (s < en) ? elist[s] : 0;
    for (int j = s; j < en; ++j) {
        int idxn = (j + 1 < en) ? elist[j + 1] : 0;   // prefetch next incidence id
        int n = node_idx[idx];
        ushort4 mb = *(const ushort4*)(msg + (size_t)idx * H + c);
        float4 nv = ld4(&node_rep[(size_t)n * H + c]);
        float4 p = make_float4(bf2f(mb.x), bf2f(mb.y), bf2f(mb.z), bf2f(mb.w));
        float4 m = bnrelu4(p, sc, sf);
        macc.x += m.x; macc.y += m.y; macc.z += m.z; macc.w += m.w;
        lacc.x += nv.x; lacc.y += nv.y; lacc.z += nv.z; lacc.w += nv.w;
        idx = idxn;
    }
    st4(&catm[(size_t)e * H + c], macc);
    const float eps = eps2p[0];
    float4 er = ld4(&edge_rep[(size_t)e * H + c]);
    float4 y;
    y.x = fmaf(eps, er.x, er.x + lacc.x);
    y.y = fmaf(eps, er.y, er.y + lacc.y);
    y.z = fmaf(eps, er.z, er.z + lacc.z);
    y.w = fmaf(eps, er.w, er.w + lacc.w);
    st4(&yedge[(size_t)e * H + c], y);
}

// ---- gather_node: xnode[n]=(1+eps1)*node_rep[n] + sum_i (catm[eidx_i] - bnrelu(msg_i))
__global__ __launch_bounds__(256) void gather_node_kernel(
    const unsigned short* __restrict__ msg, const float* __restrict__ catm,
    const float* __restrict__ node_rep, const int* __restrict__ edge_idx,
    const int* __restrict__ noff, const int* __restrict__ nlist,
    const float* __restrict__ ss, const float* __restrict__ eps1p,
    float* __restrict__ xnode)
{
    const int t = threadIdx.x;
    const int sub = t >> 5;                 // 8 nodes / block
    const int lane = t & 31;
    const int n = blockIdx.x * 8 + sub;     // grid = 12500 exact
    const int c = lane * 4;
    const int s = (n == 0) ? 0 : noff[n - 1];
    const int en = noff[n];
    const float4 sc = ld4(&ss[c]);
    const float4 sf = ld4(&ss[128 + c]);
    float4 acc = make_float4(0.f, 0.f, 0.f, 0.f);
    int idx = (s < en) ? nlist[s] : 0;
    for (int j = s; j < en; ++j) {
        int idxn = (j + 1 < en) ? nlist[j + 1] : 0;
        int e = edge_idx[idx];
        ushort4 mb = *(const ushort4*)(msg + (size_t)idx * H + c);
        float4 cv = ld4(&catm[(size_t)e * H + c]);
        float4 p = make_float4(bf2f(mb.x), bf2f(mb.y), bf2f(mb.z), bf2f(mb.w));
        float4 m = bnrelu4(p, sc, sf);      // bit-identical to the value summed into catm
        acc.x += cv.x - m.x; acc.y += cv.y - m.y;
        acc.z += cv.z - m.z; acc.w += cv.w - m.w;
        idx = idxn;
    }
    const float eps = eps1p[0];
    float4 nr = ld4(&node_rep[(size_t)n * H + c]);
    float4 x;
    x.x = fmaf(eps, nr.x, nr.x + acc.x);
    x.y = fmaf(eps, nr.y, nr.y + acc.y);
    x.z = fmaf(eps, nr.z, nr.z + acc.z);
    x.w = fmaf(eps, nr.w, nr.w + acc.w);
    st4(&xnode[(size_t)n * H + c], x);
}

// ---- final bn_relu apply -> fp32 out ----
__global__ __launch_bounds__(256) void apply_kernel(const float* __restrict__ pre,
                                                    const float* __restrict__ ss,
                                                    float* __restrict__ out, int M)
{
    size_t gid = (size_t)blockIdx.x * 256 + threadIdx.x;
    size_t r = gid >> 5;
    int c = (int)(gid & 31) * 4;
    if (r >= (size_t)M) return;
    float4 p = ld4(&pre[r * H + c]);
    float4 sc = ld4(&ss[c]);
    float4 sf = ld4(&ss[128 + c]);
    st4(&out[r * H + c], bnrelu4(p, sc, sf));
}

extern "C" void kernel_launch(void* const* d_in, const int* in_sizes, int n_in,
                              void* d_out, int out_size, void* d_ws, size_t ws_size,
                              hipStream_t stream)
{
    const float* node_rep = (const float*)d_in[0];
    const float* edge_rep = (const float*)d_in[1];
    const int*   node_idx = (const int*)d_in[2];
    const int*   edge_idx = (const int*)d_in[3];
    const float* W1  = (const float*)d_in[4];
    const float* g1  = (const float*)d_in[5];
    const float* b1  = (const float*)d_in[6];
    const float* W2a = (const float*)d_in[7];
    const float* g2a = (const float*)d_in[8];
    const float* b2a = (const float*)d_in[9];
    const float* W2b = (const float*)d_in[10];
    const float* g2b = (const float*)d_in[11];
    const float* b2b = (const float*)d_in[12];
    const float* W3a = (const float*)d_in[13];
    const float* g3a = (const float*)d_in[14];
    const float* b3a = (const float*)d_in[15];
    const float* W3b = (const float*)d_in[16];
    const float* g3b = (const float*)d_in[17];
    const float* b3b = (const float*)d_in[18];
    const float* eps1 = (const float*)d_in[19];
    const float* eps2 = (const float*)d_in[20];

    float* ws = (float*)d_ws;
    // layout (float-slot offsets):
    unsigned short* msgb = (unsigned short*)ws;        // 800000*128 bf16 (51.2M slots)
    float* catm  = ws + (size_t) 51200000;             // 400000*128 f
    float* yedge = ws + (size_t)102400000;             // 400000*128 f
    float* xnode = ws + (size_t)153600000;             // 100000*128 f
    // edge CSR lives in the xnode region (dead before gather_node writes xnode):
    int* eoff  = (int*)(ws + (size_t)153600000);       // 400000
    int* elist = (int*)(ws + (size_t)154000000);       // 800000
    float* stat = ws + (size_t)166400000;              // 5*256 sums + 5*256 ss
    int* noff  = (int*)(ws + (size_t)166402560);       // 100000
    int* nlist = (int*)(ws + (size_t)166502560);       // 800000
    int* eaux  = (int*)(ws + (size_t)167302560);       // 256
    int* naux  = (int*)(ws + (size_t)167302816);       // 256
    // transposed bf16 weights:
    unsigned short* wt1  = (unsigned short*)(ws + (size_t)167304000);  // 128*256 bf16
    unsigned short* wt2a = (unsigned short*)(ws + (size_t)167320384);  // 128*128 bf16
    unsigned short* wt2b = (unsigned short*)(ws + (size_t)167328576);
    unsigned short* wt3a = (unsigned short*)(ws + (size_t)167336768);
    unsigned short* wt3b = (unsigned short*)(ws + (size_t)167344960);

    // post-gather reuse:
    float* e1 = catm;           // first edge-gemm out (catm dead after gather_node)
    float* e2 = (float*)msgb;   // second edge-gemm out (msgb dead after gather_node)
    float* n1 = catm;           // first node-gemm out (e1 dead after second edge gemm)
    float* n2 = catm + (size_t)12800000;

    float* sums0 = stat +    0; float* ss0 = stat + 1280;
    float* sums1 = stat +  256; float* ss1 = stat + 1536;
    float* sums2 = stat +  512; float* ss2 = stat + 1792;
    float* sums3 = stat +  768; float* ss3 = stat + 2048;
    float* sums4 = stat + 1024; float* ss4 = stat + 2304;

    float* out_node = (float*)d_out;
    float* out_edge = out_node + (size_t)N_NODES * H;

    // tiny zero-inits only
    hipMemsetAsync(stat, 0, 1280 * sizeof(float), stream);
    hipMemsetAsync(eoff, 0, (size_t)N_EDGES * sizeof(int), stream);
    hipMemsetAsync(noff, 0, (size_t)N_NODES * sizeof(int), stream);

    // ---- weight transpose + bf16 (tiny) ----
    wtrans_kernel<<<128, 256, 0, stream>>>(W1,  wt1,  8);
    wtrans_kernel<<< 64, 256, 0, stream>>>(W2a, wt2a, 7);
    wtrans_kernel<<< 64, 256, 0, stream>>>(W2b, wt2b, 7);
    wtrans_kernel<<< 64, 256, 0, stream>>>(W3a, wt3a, 7);
    wtrans_kernel<<< 64, 256, 0, stream>>>(W3b, wt3b, 7);

    // ---- CSR build: edges (196 scan blocks) and nodes (49 scan blocks) ----
    hist_kernel<<<N_INC / 256, 256, 0, stream>>>(edge_idx, eoff, N_INC);
    scan_block_kernel<<<196, 256, 0, stream>>>(eoff, N_EDGES, eaux);
    scan_block_kernel<<<1, 256, 0, stream>>>(eaux, 196, nullptr);
    scan_add_kernel<<<(N_EDGES + 255) / 256, 256, 0, stream>>>(eoff, N_EDGES, eaux);
    fill_kernel<<<N_INC / 256, 256, 0, stream>>>(edge_idx, eoff, elist, N_INC);

    hist_kernel<<<N_INC / 256, 256, 0, stream>>>(node_idx, noff, N_INC);
    scan_block_kernel<<<49, 256, 0, stream>>>(noff, N_NODES, naux);
    scan_block_kernel<<<1, 256, 0, stream>>>(naux, 49, nullptr);
    scan_add_kernel<<<(N_NODES + 255) / 256, 256, 0, stream>>>(noff, N_NODES, naux);
    fill_kernel<<<N_INC / 256, 256, 0, stream>>>(node_idx, noff, nlist, N_INC);

    // ---- layer 1: gathered concat GEMM (direct MFMA, fused stats) -> bf16 msg ----
    gemm1_mfma<<<N_INC / 128, 256, 0, stream>>>(node_rep, edge_rep, node_idx, edge_idx,
                                                wt1, msgb, sums0);
    finalize_kernel<<<1, 128, 0, stream>>>(sums0, 1.0f / N_INC, g1, b1, ss0);

    // ---- dense gathers (BN1 fused; y/x residual fused) ----
    gather_edge_kernel<<<N_EDGES / 8, 256, 0, stream>>>(msgb, node_rep, edge_rep, node_idx,
                                                        eoff, elist, ss0, eps2, catm, yedge);
    gather_node_kernel<<<N_NODES / 8, 256, 0, stream>>>(msgb, catm, node_rep, edge_idx,
                                                        noff, nlist, ss0, eps1, xnode);

    // ---- edge head: yedge @ W3a -> e1; bnrelu(e1) @ W3b -> e2; apply ----
    gemmh_mfma<<<N_EDGES / 128, 256, 0, stream>>>(N_EDGES, 0, yedge, nullptr, wt3a, e1, sums3);
    finalize_kernel<<<1, 128, 0, stream>>>(sums3, 1.0f / N_EDGES, g3a, b3a, ss3);
    gemmh_mfma<<<N_EDGES / 128, 256, 0, stream>>>(N_EDGES, 2, e1, ss3, wt3b, e2, sums4);
    finalize_kernel<<<1, 128, 0, stream>>>(sums4, 1.0f / N_EDGES, g3b, b3b, ss4);
    apply_kernel<<<N_EDGES / 8, 256, 0, stream>>>(e2, ss4, out_edge, N_EDGES);

    // ---- node head: xnode @ W2a -> n1; bnrelu(n1) @ W2b -> n2; apply ----
    gemmh_mfma<<<(N_NODES + 127) / 128, 256, 0, stream>>>(N_NODES, 0, xnode, nullptr, wt2a, n1, sums1);
    finalize_kernel<<<1, 128, 0, stream>>>(sums1, 1.0f / N_NODES, g2a, b2a, ss1);
    gemmh_mfma<<<(N_NODES + 127) / 128, 256, 0, stream>>>(N_NODES, 2, n1, ss1, wt2b, n2, sums2);
    finalize_kernel<<<1, 128, 0, stream>>>(sums2, 1.0f / N_NODES, g2b, b2b, ss2);
    apply_kernel<<<N_NODES / 8, 256, 0, stream>>>(n2, ss2, out_node, N_NODES);
}

// Round 4
// 1715.131 us; speedup vs baseline: 3.7818x; 1.0623x over previous
//
#include <hip/hip_runtime.h>

#define H 128
#define N_NODES 100000
#define N_EDGES 400000
#define N_INC   800000
#define BN_EPS 1e-5f

typedef __attribute__((ext_vector_type(8))) __bf16 bf16x8;
typedef __attribute__((ext_vector_type(4))) float f32x4;

__device__ __forceinline__ float4 ld4(const float* p) { return *(const float4*)p; }
__device__ __forceinline__ void st4(float* p, float4 v) { *(float4*)p = v; }
__device__ __forceinline__ float4 bnrelu4(float4 p, float4 sc, float4 sf) {
    float4 o;
    o.x = fmaxf(fmaf(p.x, sc.x, sf.x), 0.f);
    o.y = fmaxf(fmaf(p.y, sc.y, sf.y), 0.f);
    o.z = fmaxf(fmaf(p.z, sc.z, sf.z), 0.f);
    o.w = fmaxf(fmaf(p.w, sc.w, sf.w), 0.f);
    return o;
}
__device__ __forceinline__ unsigned short f2bf(float x) {   // round-to-nearest-even
    unsigned int u = __builtin_bit_cast(unsigned int, x);
    u += 0x7fffu + ((u >> 16) & 1u);
    return (unsigned short)(u >> 16);
}
__device__ __forceinline__ float bf2f(unsigned short s) {
    unsigned int u = ((unsigned int)s) << 16;
    return __builtin_bit_cast(float, u);
}

// split 8 fp32 into hi/lo bf16x8 (compiler emits v_cvt_pk_bf16_f32 for the casts)
__device__ __forceinline__ void split8(const float* a, bf16x8& h, bf16x8& l) {
#pragma unroll
    for (int j = 0; j < 8; ++j) h[j] = (__bf16)a[j];
#pragma unroll
    for (int j = 0; j < 8; ++j) l[j] = (__bf16)(a[j] - (float)h[j]);
}

// ---- W transpose + bf16 convert: Wt[n*K + k] = bf16(W[k*128 + n]) ----
__global__ void wtrans_kernel(const float* __restrict__ W, unsigned short* __restrict__ Wt,
                              int kbits)
{
    int i = blockIdx.x * 256 + threadIdx.x;   // grid sized exactly to 128<<kbits
    int K = 1 << kbits;
    int n = i >> kbits;
    int k = i & (K - 1);
    Wt[i] = f2bf(W[(size_t)k * H + n]);
}

// ======================= MFMA GEMMs: W in LDS (staged once), A direct global =======================
// 256 threads = 4 waves; wave w owns rows [tile*128 + w*32, +32): 2 row-tiles x 8 col-tiles.
// Grid-stride over row tiles; NO barriers in the K loop; depth-2 A prefetch.
// LDS W swizzle (ushort granularity 8): idx = n*K + (k ^ ((n&7)<<3))  -> 2-way max on ds_read_b128 (free).
// BN column stats accumulated in registers across all row tiles, reduced once per block at the end.

// ---- GEMM1: gathered concat [node_rep[nidx]|edge_rep[eidx]] (800000x256) @ W1 -> bf16 msg ----
__global__ __launch_bounds__(256) void gemm1_mfma(
    const float* __restrict__ node_rep, const float* __restrict__ edge_rep,
    const int* __restrict__ node_idx, const int* __restrict__ edge_idx,
    const unsigned short* __restrict__ Wt,   // [128 n][256 k] bf16
    unsigned short* __restrict__ out, float* __restrict__ sums)
{
    __shared__ unsigned short Wl[128 * 256];   // 64 KB
    const int tid = threadIdx.x;
    const int lane = tid & 63;
    const int wv = tid >> 6;
    const int l15 = lane & 15;
    const int kb = lane >> 4;
    const int ko = kb * 8;
    const int swz = (l15 & 7) << 3;           // n&7 == l15&7 for n = ct*16+l15

    // stage W once: 4096 groups of 8 ushorts
#pragma unroll
    for (int it = 0; it < 16; ++it) {
        int g = it * 256 + tid;
        int n = g >> 5, k8 = (g & 31) * 8;
        *(uint4*)&Wl[n * 256 + (k8 ^ ((n & 7) << 3))] = *(const uint4*)&Wt[(size_t)n * 256 + k8];
    }
    __syncthreads();

    float scol[8], qcol[8];
#pragma unroll
    for (int ct = 0; ct < 8; ++ct) { scol[ct] = 0.f; qcol[ct] = 0.f; }

    for (int rb = blockIdx.x; rb < N_INC / 128; rb += gridDim.x) {
        const int rowBase = rb * 128 + wv * 32;
        const int r0 = rowBase + l15;
        const int r1 = rowBase + 16 + l15;
        const float* an0 = node_rep + (size_t)node_idx[r0] * H + ko;
        const float* ae0 = edge_rep + (size_t)edge_idx[r0] * H + ko;
        const float* an1 = node_rep + (size_t)node_idx[r1] * H + ko;
        const float* ae1 = edge_rep + (size_t)edge_idx[r1] * H + ko;

        f32x4 acc[2][8];
#pragma unroll
        for (int i = 0; i < 2; ++i)
#pragma unroll
            for (int j = 0; j < 8; ++j) acc[i][j] = (f32x4){0.f, 0.f, 0.f, 0.f};

        float4 ab[3][2][2];
        ab[0][0][0] = ld4(an0);      ab[0][0][1] = ld4(an0 + 4);
        ab[0][1][0] = ld4(an1);      ab[0][1][1] = ld4(an1 + 4);
        ab[1][0][0] = ld4(an0 + 32); ab[1][0][1] = ld4(an0 + 36);
        ab[1][1][0] = ld4(an1 + 32); ab[1][1][1] = ld4(an1 + 36);

#pragma unroll
        for (int ks = 0; ks < 8; ++ks) {
            if (ks < 6) {                       // depth-2 prefetch
                const int kf = (ks + 2) * 32;
                const float* p0 = (ks + 2 < 4) ? an0 + kf : ae0 + (kf - 128);
                const float* p1 = (ks + 2 < 4) ? an1 + kf : ae1 + (kf - 128);
                const int slot = (ks + 2) % 3;
                ab[slot][0][0] = ld4(p0); ab[slot][0][1] = ld4(p0 + 4);
                ab[slot][1][0] = ld4(p1); ab[slot][1][1] = ld4(p1 + 4);
            }
            const int cur = ks % 3;
            float a0[8] = {ab[cur][0][0].x, ab[cur][0][0].y, ab[cur][0][0].z, ab[cur][0][0].w,
                           ab[cur][0][1].x, ab[cur][0][1].y, ab[cur][0][1].z, ab[cur][0][1].w};
            float a1[8] = {ab[cur][1][0].x, ab[cur][1][0].y, ab[cur][1][0].z, ab[cur][1][0].w,
                           ab[cur][1][1].x, ab[cur][1][1].y, ab[cur][1][1].z, ab[cur][1][1].w};
            bf16x8 h0, l0, h1, l1;
            split8(a0, h0, l0);
            split8(a1, h1, l1);
            const int kbase = (ks * 32 + ko) ^ swz;
#pragma unroll
            for (int ct = 0; ct < 8; ++ct) {
                bf16x8 bw = *(const bf16x8*)&Wl[(ct * 16 + l15) * 256 + kbase];
                acc[0][ct] = __builtin_amdgcn_mfma_f32_16x16x32_bf16(h0, bw, acc[0][ct], 0, 0, 0);
                acc[0][ct] = __builtin_amdgcn_mfma_f32_16x16x32_bf16(l0, bw, acc[0][ct], 0, 0, 0);
                acc[1][ct] = __builtin_amdgcn_mfma_f32_16x16x32_bf16(h1, bw, acc[1][ct], 0, 0, 0);
                acc[1][ct] = __builtin_amdgcn_mfma_f32_16x16x32_bf16(l1, bw, acc[1][ct], 0, 0, 0);
            }
        }

        // epilogue: bf16 store + stats accumulation (on rounded values)
#pragma unroll
        for (int rt = 0; rt < 2; ++rt) {
            const int rg0 = rowBase + rt * 16 + kb * 4;
#pragma unroll
            for (int j = 0; j < 4; ++j) {
#pragma unroll
                for (int ct = 0; ct < 8; ++ct) {
                    unsigned short us = f2bf(acc[rt][ct][j]);
                    out[(size_t)(rg0 + j) * H + ct * 16 + l15] = us;
                    float v = bf2f(us);
                    scol[ct] += v;
                    qcol[ct] = fmaf(v, v, qcol[ct]);
                }
            }
        }
    }

    // block stats reduce (reuse Wl as scratch)
#pragma unroll
    for (int ct = 0; ct < 8; ++ct) {
        scol[ct] += __shfl_xor(scol[ct], 16);
        scol[ct] += __shfl_xor(scol[ct], 32);
        qcol[ct] += __shfl_xor(qcol[ct], 16);
        qcol[ct] += __shfl_xor(qcol[ct], 32);
    }
    __syncthreads();
    float* sred = (float*)Wl;
    if (kb == 0) {
#pragma unroll
        for (int ct = 0; ct < 8; ++ct) {
            sred[wv * 256 + ct * 16 + l15] = scol[ct];
            sred[wv * 256 + 128 + ct * 16 + l15] = qcol[ct];
        }
    }
    __syncthreads();
    float tot = sred[tid] + sred[256 + tid] + sred[512 + tid] + sred[768 + tid];
    atomicAdd(&sums[tid], tot);
}

// ---- Head GEMM: Mx128 @ 128x128. mode 0: A=A0; mode 2: A=relu(A0*scale+shift). fp32 out + stats ----
__global__ __launch_bounds__(256, 3) void gemmh_mfma(
    int M, int mode, const float* __restrict__ A0, const float* __restrict__ ss,
    const unsigned short* __restrict__ Wt,   // [128 n][128 k] bf16
    float* __restrict__ out, float* __restrict__ sums)
{
    __shared__ unsigned short Wl[128 * 128];   // 32 KB
    const int tid = threadIdx.x;
    const int lane = tid & 63;
    const int wv = tid >> 6;
    const int l15 = lane & 15;
    const int kb = lane >> 4;
    const int ko = kb * 8;
    const int swz = (l15 & 7) << 3;
    const int nTiles = (M + 127) >> 7;

#pragma unroll
    for (int it = 0; it < 8; ++it) {
        int g = it * 256 + tid;
        int n = g >> 4, k8 = (g & 15) * 8;
        *(uint4*)&Wl[n * 128 + (k8 ^ ((n & 7) << 3))] = *(const uint4*)&Wt[(size_t)n * 128 + k8];
    }
    __syncthreads();

    float scol[8], qcol[8];
#pragma unroll
    for (int ct = 0; ct < 8; ++ct) { scol[ct] = 0.f; qcol[ct] = 0.f; }

    for (int rb = blockIdx.x; rb < nTiles; rb += gridDim.x) {
        const int rowBase = rb * 128 + wv * 32;
        int r0 = rowBase + l15;       if (r0 >= M) r0 = M - 1;
        int r1 = rowBase + 16 + l15;  if (r1 >= M) r1 = M - 1;
        const float* a0p = A0 + (size_t)r0 * H + ko;
        const float* a1p = A0 + (size_t)r1 * H + ko;

        f32x4 acc[2][8];
#pragma unroll
        for (int i = 0; i < 2; ++i)
#pragma unroll
            for (int j = 0; j < 8; ++j) acc[i][j] = (f32x4){0.f, 0.f, 0.f, 0.f};

        float4 ab[3][2][2];
        ab[0][0][0] = ld4(a0p);      ab[0][0][1] = ld4(a0p + 4);
        ab[0][1][0] = ld4(a1p);      ab[0][1][1] = ld4(a1p + 4);
        ab[1][0][0] = ld4(a0p + 32); ab[1][0][1] = ld4(a0p + 36);
        ab[1][1][0] = ld4(a1p + 32); ab[1][1][1] = ld4(a1p + 36);

#pragma unroll
        for (int ks = 0; ks < 4; ++ks) {
            if (ks < 2) {
                const int kf = (ks + 2) * 32;
                const int slot = (ks + 2) % 3;
                ab[slot][0][0] = ld4(a0p + kf); ab[slot][0][1] = ld4(a0p + kf + 4);
                ab[slot][1][0] = ld4(a1p + kf); ab[slot][1][1] = ld4(a1p + kf + 4);
            }
            const int cur = ks % 3;
            float a0[8] = {ab[cur][0][0].x, ab[cur][0][0].y, ab[cur][0][0].z, ab[cur][0][0].w,
                           ab[cur][0][1].x, ab[cur][0][1].y, ab[cur][0][1].z, ab[cur][0][1].w};
            float a1[8] = {ab[cur][1][0].x, ab[cur][1][0].y, ab[cur][1][0].z, ab[cur][1][0].w,
                           ab[cur][1][1].x, ab[cur][1][1].y, ab[cur][1][1].z, ab[cur][1][1].w};
            if (mode == 2) {
                const int k0 = ks * 32 + ko;
                float4 sca = ld4(&ss[k0]), scb = ld4(&ss[k0 + 4]);
                float4 sfa = ld4(&ss[128 + k0]), sfb = ld4(&ss[128 + k0 + 4]);
                float sc[8] = {sca.x, sca.y, sca.z, sca.w, scb.x, scb.y, scb.z, scb.w};
                float sf[8] = {sfa.x, sfa.y, sfa.z, sfa.w, sfb.x, sfb.y, sfb.z, sfb.w};
#pragma unroll
                for (int j = 0; j < 8; ++j) {
                    a0[j] = fmaxf(fmaf(a0[j], sc[j], sf[j]), 0.f);
                    a1[j] = fmaxf(fmaf(a1[j], sc[j], sf[j]), 0.f);
                }
            }
            bf16x8 h0, l0, h1, l1;
            split8(a0, h0, l0);
            split8(a1, h1, l1);
            const int kbase = (ks * 32 + ko) ^ swz;
#pragma unroll
            for (int ct = 0; ct < 8; ++ct) {
                bf16x8 bw = *(const bf16x8*)&Wl[(ct * 16 + l15) * 128 + kbase];
                acc[0][ct] = __builtin_amdgcn_mfma_f32_16x16x32_bf16(h0, bw, acc[0][ct], 0, 0, 0);
                acc[0][ct] = __builtin_amdgcn_mfma_f32_16x16x32_bf16(l0, bw, acc[0][ct], 0, 0, 0);
                acc[1][ct] = __builtin_amdgcn_mfma_f32_16x16x32_bf16(h1, bw, acc[1][ct], 0, 0, 0);
                acc[1][ct] = __builtin_amdgcn_mfma_f32_16x16x32_bf16(l1, bw, acc[1][ct], 0, 0, 0);
            }
        }

#pragma unroll
        for (int rt = 0; rt < 2; ++rt) {
#pragma unroll
            for (int j = 0; j < 4; ++j) {
                const int rg = rowBase + rt * 16 + kb * 4 + j;
                if (rg < M) {
#pragma unroll
                    for (int ct = 0; ct < 8; ++ct) {
                        float v = acc[rt][ct][j];
                        out[(size_t)rg * H + ct * 16 + l15] = v;
                        scol[ct] += v;
                        qcol[ct] = fmaf(v, v, qcol[ct]);
                    }
                }
            }
        }
    }

#pragma unroll
    for (int ct = 0; ct < 8; ++ct) {
        scol[ct] += __shfl_xor(scol[ct], 16);
        scol[ct] += __shfl_xor(scol[ct], 32);
        qcol[ct] += __shfl_xor(qcol[ct], 16);
        qcol[ct] += __shfl_xor(qcol[ct], 32);
    }
    __syncthreads();
    float* sred = (float*)Wl;
    if (kb == 0) {
#pragma unroll
        for (int ct = 0; ct < 8; ++ct) {
            sred[wv * 256 + ct * 16 + l15] = scol[ct];
            sred[wv * 256 + 128 + ct * 16 + l15] = qcol[ct];
        }
    }
    __syncthreads();
    float tot = sred[tid] + sred[256 + tid] + sred[512 + tid] + sred[768 + tid];
    atomicAdd(&sums[tid], tot);
}

__global__ void finalize_kernel(const float* __restrict__ sums, float invM,
                                const float* __restrict__ g, const float* __restrict__ b,
                                float* __restrict__ ss)
{
    int c = threadIdx.x;  // 128 threads
    float mean = sums[c] * invM;
    float var = fmaf(-mean, mean, sums[128 + c] * invM);
    float scale = g[c] * rsqrtf(var + BN_EPS);
    ss[c] = scale;
    ss[128 + c] = fmaf(-mean, scale, b[c]);
}

// ======================= CSR build (no atomic scatter!) =======================
__global__ void hist_kernel(const int* __restrict__ idx, int* __restrict__ cnt, int n)
{
    int i = blockIdx.x * 256 + threadIdx.x;
    if (i < n) atomicAdd(&cnt[idx[i]], 1);
}

// in-place exclusive block scan; 2048 elems/block; block totals -> aux (if non-null)
__global__ __launch_bounds__(256) void scan_block_kernel(int* __restrict__ a, int n,
                                                         int* __restrict__ aux)
{
    __shared__ int sh[2048];
    __shared__ int ts[256];
    const int t = threadIdx.x;
    const int base = blockIdx.x * 2048;
#pragma unroll
    for (int k = 0; k < 8; ++k) {
        int i = base + t + k * 256;
        sh[t + k * 256] = (i < n) ? a[i] : 0;
    }
    __syncthreads();
    int loc[8], sum = 0;
#pragma unroll
    for (int k = 0; k < 8; ++k) { loc[k] = sh[t * 8 + k]; sum += loc[k]; }
    ts[t] = sum;
    __syncthreads();
    for (int o = 1; o < 256; o <<= 1) {
        int v = (t >= o) ? ts[t - o] : 0;
        __syncthreads();
        ts[t] += v;
        __syncthreads();
    }
    int run = ts[t] - sum;  // exclusive prefix of this thread's chunk
#pragma unroll
    for (int k = 0; k < 8; ++k) {
        int i = base + t * 8 + k;
        if (i < n) a[i] = run;
        run += loc[k];
    }
    if (aux != nullptr && t == 255) aux[blockIdx.x] = ts[255];
}

__global__ void scan_add_kernel(int* __restrict__ a, int n, const int* __restrict__ aux)
{
    int i = blockIdx.x * 256 + threadIdx.x;
    if (i < n) a[i] += aux[i >> 11];
}

// after fill: off[s] = end(s); gather uses [s==0?0:off[s-1], off[s])
__global__ void fill_kernel(const int* __restrict__ idx, int* __restrict__ off,
                            int* __restrict__ list, int n)
{
    int i = blockIdx.x * 256 + threadIdx.x;
    if (i < n) {
        int p = atomicAdd(&off[idx[i]], 1);
        list[p] = i;
    }
}

// ---- gather_edge: catm[e]=sum bnrelu(msg_i); yedge[e]=(1+eps2)*edge_rep[e]+sum node_rep[nidx_i]
__global__ __launch_bounds__(256) void gather_edge_kernel(
    const unsigned short* __restrict__ msg, const float* __restrict__ node_rep,
    const float* __restrict__ edge_rep, const int* __restrict__ node_idx,
    const int* __restrict__ eoff, const int* __restrict__ elist,
    const float* __restrict__ ss, const float* __restrict__ eps2p,
    float* __restrict__ catm, float* __restrict__ yedge)
{
    const int t = threadIdx.x;
    const int sub = t >> 5;                 // 8 edges / block
    const int lane = t & 31;
    const int e = blockIdx.x * 8 + sub;     // grid = 50000 exact
    const int c = lane * 4;
    const int s = (e == 0) ? 0 : eoff[e - 1];
    const int en = eoff[e];
    const float4 sc = ld4(&ss[c]);
    const float4 sf = ld4(&ss[128 + c]);
    float4 macc = make_float4(0.f, 0.f, 0.f, 0.f);
    float4 lacc = make_float4(0.f, 0.f, 0.f, 0.f);
    int idx = (s < en) ? elist[s] : 0;
    for (int j = s; j < en; ++j) {
        int idxn = (j + 1 < en) ? elist[j + 1] : 0;   // prefetch next incidence id
        int n = node_idx[idx];
        ushort4 mb = *(const ushort4*)(msg + (size_t)idx * H + c);
        float4 nv = ld4(&node_rep[(size_t)n * H + c]);
        float4 p = make_float4(bf2f(mb.x), bf2f(mb.y), bf2f(mb.z), bf2f(mb.w));
        float4 m = bnrelu4(p, sc, sf);
        macc.x += m.x; macc.y += m.y; macc.z += m.z; macc.w += m.w;
        lacc.x += nv.x; lacc.y += nv.y; lacc.z += nv.z; lacc.w += nv.w;
        idx = idxn;
    }
    st4(&catm[(size_t)e * H + c], macc);
    const float eps = eps2p[0];
    float4 er = ld4(&edge_rep[(size_t)e * H + c]);
    float4 y;
    y.x = fmaf(eps, er.x, er.x + lacc.x);
    y.y = fmaf(eps, er.y, er.y + lacc.y);
    y.z = fmaf(eps, er.z, er.z + lacc.z);
    y.w = fmaf(eps, er.w, er.w + lacc.w);
    st4(&yedge[(size_t)e * H + c], y);
}

// ---- gather_node: xnode[n]=(1+eps1)*node_rep[n] + sum_i (catm[eidx_i] - bnrelu(msg_i))
__global__ __launch_bounds__(256) void gather_node_kernel(
    const unsigned short* __restrict__ msg, const float* __restrict__ catm,
    const float* __restrict__ node_rep, const int* __restrict__ edge_idx,
    const int* __restrict__ noff, const int* __restrict__ nlist,
    const float* __restrict__ ss, const float* __restrict__ eps1p,
    float* __restrict__ xnode)
{
    const int t = threadIdx.x;
    const int sub = t >> 5;                 // 8 nodes / block
    const int lane = t & 31;
    const int n = blockIdx.x * 8 + sub;     // grid = 12500 exact
    const int c = lane * 4;
    const int s = (n == 0) ? 0 : noff[n - 1];
    const int en = noff[n];
    const float4 sc = ld4(&ss[c]);
    const float4 sf = ld4(&ss[128 + c]);
    float4 acc = make_float4(0.f, 0.f, 0.f, 0.f);
    int idx = (s < en) ? nlist[s] : 0;
    for (int j = s; j < en; ++j) {
        int idxn = (j + 1 < en) ? nlist[j + 1] : 0;
        int e = edge_idx[idx];
        ushort4 mb = *(const ushort4*)(msg + (size_t)idx * H + c);
        float4 cv = ld4(&catm[(size_t)e * H + c]);
        float4 p = make_float4(bf2f(mb.x), bf2f(mb.y), bf2f(mb.z), bf2f(mb.w));
        float4 m = bnrelu4(p, sc, sf);      // bit-identical to the value summed into catm
        acc.x += cv.x - m.x; acc.y += cv.y - m.y;
        acc.z += cv.z - m.z; acc.w += cv.w - m.w;
        idx = idxn;
    }
    const float eps = eps1p[0];
    float4 nr = ld4(&node_rep[(size_t)n * H + c]);
    float4 x;
    x.x = fmaf(eps, nr.x, nr.x + acc.x);
    x.y = fmaf(eps, nr.y, nr.y + acc.y);
    x.z = fmaf(eps, nr.z, nr.z + acc.z);
    x.w = fmaf(eps, nr.w, nr.w + acc.w);
    st4(&xnode[(size_t)n * H + c], x);
}

// ---- final bn_relu apply -> fp32 out ----
__global__ __launch_bounds__(256) void apply_kernel(const float* __restrict__ pre,
                                                    const float* __restrict__ ss,
                                                    float* __restrict__ out, int M)
{
    size_t gid = (size_t)blockIdx.x * 256 + threadIdx.x;
    size_t r = gid >> 5;
    int c = (int)(gid & 31) * 4;
    if (r >= (size_t)M) return;
    float4 p = ld4(&pre[r * H + c]);
    float4 sc = ld4(&ss[c]);
    float4 sf = ld4(&ss[128 + c]);
    st4(&out[r * H + c], bnrelu4(p, sc, sf));
}

extern "C" void kernel_launch(void* const* d_in, const int* in_sizes, int n_in,
                              void* d_out, int out_size, void* d_ws, size_t ws_size,
                              hipStream_t stream)
{
    const float* node_rep = (const float*)d_in[0];
    const float* edge_rep = (const float*)d_in[1];
    const int*   node_idx = (const int*)d_in[2];
    const int*   edge_idx = (const int*)d_in[3];
    const float* W1  = (const float*)d_in[4];
    const float* g1  = (const float*)d_in[5];
    const float* b1  = (const float*)d_in[6];
    const float* W2a = (const float*)d_in[7];
    const float* g2a = (const float*)d_in[8];
    const float* b2a = (const float*)d_in[9];
    const float* W2b = (const float*)d_in[10];
    const float* g2b = (const float*)d_in[11];
    const float* b2b = (const float*)d_in[12];
    const float* W3a = (const float*)d_in[13];
    const float* g3a = (const float*)d_in[14];
    const float* b3a = (const float*)d_in[15];
    const float* W3b = (const float*)d_in[16];
    const float* g3b = (const float*)d_in[17];
    const float* b3b = (const float*)d_in[18];
    const float* eps1 = (const float*)d_in[19];
    const float* eps2 = (const float*)d_in[20];

    float* ws = (float*)d_ws;
    // layout (float-slot offsets):
    unsigned short* msgb = (unsigned short*)ws;        // 800000*128 bf16 (51.2M slots)
    float* catm  = ws + (size_t) 51200000;             // 400000*128 f
    float* yedge = ws + (size_t)102400000;             // 400000*128 f
    float* xnode = ws + (size_t)153600000;             // 100000*128 f
    // edge CSR lives in the xnode region (dead before gather_node writes xnode):
    int* eoff  = (int*)(ws + (size_t)153600000);       // 400000
    int* elist = (int*)(ws + (size_t)154000000);       // 800000
    float* stat = ws + (size_t)166400000;              // 5*256 sums + 5*256 ss
    int* noff  = (int*)(ws + (size_t)166402560);       // 100000
    int* nlist = (int*)(ws + (size_t)166502560);       // 800000
    int* eaux  = (int*)(ws + (size_t)167302560);       // 256
    int* naux  = (int*)(ws + (size_t)167302816);       // 256
    // transposed bf16 weights:
    unsigned short* wt1  = (unsigned short*)(ws + (size_t)167304000);  // 128*256 bf16
    unsigned short* wt2a = (unsigned short*)(ws + (size_t)167320384);  // 128*128 bf16
    unsigned short* wt2b = (unsigned short*)(ws + (size_t)167328576);
    unsigned short* wt3a = (unsigned short*)(ws + (size_t)167336768);
    unsigned short* wt3b = (unsigned short*)(ws + (size_t)167344960);

    // post-gather reuse:
    float* e1 = catm;           // first edge-gemm out (catm dead after gather_node)
    float* e2 = (float*)msgb;   // second edge-gemm out (msgb dead after gather_node)
    float* n1 = catm;           // first node-gemm out (e1 dead after second edge gemm)
    float* n2 = catm + (size_t)12800000;

    float* sums0 = stat +    0; float* ss0 = stat + 1280;
    float* sums1 = stat +  256; float* ss1 = stat + 1536;
    float* sums2 = stat +  512; float* ss2 = stat + 1792;
    float* sums3 = stat +  768; float* ss3 = stat + 2048;
    float* sums4 = stat + 1024; float* ss4 = stat + 2304;

    float* out_node = (float*)d_out;
    float* out_edge = out_node + (size_t)N_NODES * H;

    // tiny zero-inits only
    hipMemsetAsync(stat, 0, 1280 * sizeof(float), stream);
    hipMemsetAsync(eoff, 0, (size_t)N_EDGES * sizeof(int), stream);
    hipMemsetAsync(noff, 0, (size_t)N_NODES * sizeof(int), stream);

    // ---- weight transpose + bf16 (tiny) ----
    wtrans_kernel<<<128, 256, 0, stream>>>(W1,  wt1,  8);
    wtrans_kernel<<< 64, 256, 0, stream>>>(W2a, wt2a, 7);
    wtrans_kernel<<< 64, 256, 0, stream>>>(W2b, wt2b, 7);
    wtrans_kernel<<< 64, 256, 0, stream>>>(W3a, wt3a, 7);
    wtrans_kernel<<< 64, 256, 0, stream>>>(W3b, wt3b, 7);

    // ---- CSR build: edges (196 scan blocks) and nodes (49 scan blocks) ----
    hist_kernel<<<N_INC / 256, 256, 0, stream>>>(edge_idx, eoff, N_INC);
    scan_block_kernel<<<196, 256, 0, stream>>>(eoff, N_EDGES, eaux);
    scan_block_kernel<<<1, 256, 0, stream>>>(eaux, 196, nullptr);
    scan_add_kernel<<<(N_EDGES + 255) / 256, 256, 0, stream>>>(eoff, N_EDGES, eaux);
    fill_kernel<<<N_INC / 256, 256, 0, stream>>>(edge_idx, eoff, elist, N_INC);

    hist_kernel<<<N_INC / 256, 256, 0, stream>>>(node_idx, noff, N_INC);
    scan_block_kernel<<<49, 256, 0, stream>>>(noff, N_NODES, naux);
    scan_block_kernel<<<1, 256, 0, stream>>>(naux, 49, nullptr);
    scan_add_kernel<<<(N_NODES + 255) / 256, 256, 0, stream>>>(noff, N_NODES, naux);
    fill_kernel<<<N_INC / 256, 256, 0, stream>>>(node_idx, noff, nlist, N_INC);

    // ---- layer 1: gathered concat GEMM (W-in-LDS MFMA, fused stats) -> bf16 msg ----
    gemm1_mfma<<<512, 256, 0, stream>>>(node_rep, edge_rep, node_idx, edge_idx,
                                        wt1, msgb, sums0);
    finalize_kernel<<<1, 128, 0, stream>>>(sums0, 1.0f / N_INC, g1, b1, ss0);

    // ---- dense gathers (BN1 fused; y/x residual fused) ----
    gather_edge_kernel<<<N_EDGES / 8, 256, 0, stream>>>(msgb, node_rep, edge_rep, node_idx,
                                                        eoff, elist, ss0, eps2, catm, yedge);
    gather_node_kernel<<<N_NODES / 8, 256, 0, stream>>>(msgb, catm, node_rep, edge_idx,
                                                        noff, nlist, ss0, eps1, xnode);

    // ---- edge head: yedge @ W3a -> e1; bnrelu(e1) @ W3b -> e2; apply ----
    gemmh_mfma<<<768, 256, 0, stream>>>(N_EDGES, 0, yedge, nullptr, wt3a, e1, sums3);
    finalize_kernel<<<1, 128, 0, stream>>>(sums3, 1.0f / N_EDGES, g3a, b3a, ss3);
    gemmh_mfma<<<768, 256, 0, stream>>>(N_EDGES, 2, e1, ss3, wt3b, e2, sums4);
    finalize_kernel<<<1, 128, 0, stream>>>(sums4, 1.0f / N_EDGES, g3b, b3b, ss4);
    apply_kernel<<<N_EDGES / 8, 256, 0, stream>>>(e2, ss4, out_edge, N_EDGES);

    // ---- node head: xnode @ W2a -> n1; bnrelu(n1) @ W2b -> n2; apply ----
    gemmh_mfma<<<768, 256, 0, stream>>>(N_NODES, 0, xnode, nullptr, wt2a, n1, sums1);
    finalize_kernel<<<1, 128, 0, stream>>>(sums1, 1.0f / N_NODES, g2a, b2a, ss1);
    gemmh_mfma<<<768, 256, 0, stream>>>(N_NODES, 2, n1, ss1, wt2b, n2, sums2);
    finalize_kernel<<<1, 128, 0, stream>>>(sums2, 1.0f / N_NODES, g2b, b2b, ss2);
    apply_kernel<<<N_NODES / 8, 256, 0, stream>>>(n2, ss2, out_node, N_NODES);
}